// Round 4
// baseline (1071.629 us; speedup 1.0000x reference)
//
#include <hip/hip_runtime.h>
#include <hip/hip_bf16.h>
#include <math.h>

#define HNUM 16
#define DH 64
#define NSEQ 1024
#define BATCH 2
#define DMODEL 1024
#define SCALE 0.125f
#define EPS 1e-6f
#define NUM_ITER 4

typedef float f32x4 __attribute__((ext_vector_type(4)));
typedef short bfrag __attribute__((ext_vector_type(8)));   // 8 bf16 in 4 VGPRs

__device__ inline float bf2f_u(unsigned short u) {
    unsigned int x = ((unsigned int)u) << 16;
    return __builtin_bit_cast(float, x);
}
__device__ inline unsigned short f2bf_u(float f) {
    return __builtin_bit_cast(unsigned short, __float2bfloat16(f));
}

// ---------------------------------------------------------------------------
// fp32 -> bf16 cast, vectorized (float4 in, 4x bf16 out). n % 4 == 0.
// ---------------------------------------------------------------------------
__global__ __launch_bounds__(256) void cast_f32_bf16(const float* __restrict__ src,
                                                     __hip_bfloat16* __restrict__ dst,
                                                     int n) {
    const int stride = gridDim.x * blockDim.x;
    for (int idx = blockIdx.x * blockDim.x + threadIdx.x; idx * 4 < n; idx += stride) {
        const float4 v = *reinterpret_cast<const float4*>(&src[idx * 4]);
        ushort4 o;
        o.x = f2bf_u(v.x); o.y = f2bf_u(v.y); o.z = f2bf_u(v.z); o.w = f2bf_u(v.w);
        *reinterpret_cast<ushort4*>(&dst[idx * 4]) = o;
    }
}

// ---------------------------------------------------------------------------
// C[M,Nc] (fp32) = A[M,K] @ B[Nc,K]^T, A/B bf16 row-major K-contiguous.
// 128x128 tile, BK=64, 256 thr / 4 waves, per wave 64x64 = 4x4 frags of
// mfma_f32_16x16x32_bf16.  LDS rows padded to 72 elems (144B = 9*16B): frag
// ds_read_b128 lands 2-way bank aliased (free, m136).
// ---------------------------------------------------------------------------
__global__ __launch_bounds__(256) void gemm_bt_bf16(const __hip_bfloat16* __restrict__ A,
                                                    const __hip_bfloat16* __restrict__ B,
                                                    float* __restrict__ C,
                                                    int M, int Nc, int K) {
    __shared__ __align__(16) __hip_bfloat16 As[128][72];
    __shared__ __align__(16) __hip_bfloat16 Bs[128][72];
    const int tid  = threadIdx.x;
    const int l    = tid & 63;
    const int wave = tid >> 6;
    const int m0 = blockIdx.y * 128, n0 = blockIdx.x * 128;
    const int wr = (wave >> 1) * 64, wc = (wave & 1) * 64;
    const int lr = l & 15;           // frag row/col within 16
    const int lk = (l >> 4) * 8;     // frag k-offset

    f32x4 acc[4][4];
#pragma unroll
    for (int m = 0; m < 4; ++m)
#pragma unroll
        for (int n = 0; n < 4; ++n) acc[m][n] = (f32x4){0.f, 0.f, 0.f, 0.f};

    for (int k0 = 0; k0 < K; k0 += 64) {
        // stage 128x64 bf16 tiles: 1024 chunks of 16B each, 4 per thread
#pragma unroll
        for (int p = 0; p < 4; ++p) {
            const int idx = tid + p * 256;       // 0..1023
            const int r   = idx >> 3;            // 0..127
            const int ce  = (idx & 7) * 8;       // elem col 0..56
            const uint4 av = *reinterpret_cast<const uint4*>(
                &A[(size_t)(m0 + r) * K + k0 + ce]);
            *reinterpret_cast<uint4*>(&As[r][ce]) = av;
            const uint4 bv = *reinterpret_cast<const uint4*>(
                &B[(size_t)(n0 + r) * K + k0 + ce]);
            *reinterpret_cast<uint4*>(&Bs[r][ce]) = bv;
        }
        __syncthreads();

#pragma unroll
        for (int kk = 0; kk < 64; kk += 32) {
            bfrag af[4], bfr[4];
#pragma unroll
            for (int m = 0; m < 4; ++m)
                af[m] = *reinterpret_cast<const bfrag*>(&As[wr + m * 16 + lr][kk + lk]);
#pragma unroll
            for (int n = 0; n < 4; ++n)
                bfr[n] = *reinterpret_cast<const bfrag*>(&Bs[wc + n * 16 + lr][kk + lk]);
#pragma unroll
            for (int m = 0; m < 4; ++m)
#pragma unroll
                for (int n = 0; n < 4; ++n)
                    acc[m][n] = __builtin_amdgcn_mfma_f32_16x16x32_bf16(
                        af[m], bfr[n], acc[m][n], 0, 0, 0);
        }
        __syncthreads();
    }

    // C/D layout (m89-verified): col = l&15, row = (l>>4)*4 + j
#pragma unroll
    for (int m = 0; m < 4; ++m) {
        const int row0 = m0 + wr + m * 16 + (l >> 4) * 4;
#pragma unroll
        for (int n = 0; n < 4; ++n) {
            const int col = n0 + wc + n * 16 + lr;
#pragma unroll
            for (int j = 0; j < 4; ++j)
                C[(size_t)(row0 + j) * Nc + col] = acc[m][n][j];
        }
    }
}

// ---------------------------------------------------------------------------
// Stieltjes attention, one wave per ROW-PAIR (i, 1023-i) of the same (b,h):
// constant per-wave FLOP count (perfect balance), shared K-row loads, 2x ILP
// in Newton.  Masked scores use s=-1e30 => rcp ~ 1e-30 ~ 0, so Newton/weight
// passes need no masks.  Weights staged to LDS as bf16; PV lane owns dim l.
// qkv: [B*N, 3*DMODEL] fp32.  obf out: [B,N,H*DH] bf16.
// ---------------------------------------------------------------------------
__global__ __launch_bounds__(256) void stieltjes_attn_pair(const float* __restrict__ qkv,
                                                           __hip_bfloat16* __restrict__ obf) {
    const int wid  = threadIdx.x >> 6;
    const int lane = threadIdx.x & 63;
    const int pr = blockIdx.x * 4 + wid;        // 0 .. B*H*512-1
    const int i  = pr & 511;
    const int h  = (pr >> 9) & (HNUM - 1);
    const int b  = pr >> 13;
    const int iA = i;                           // 0..511
    const int iB = (NSEQ - 1) - i;              // 512..1023

    const size_t rs = 3 * DMODEL;
    const float* kbase = qkv + (size_t)(b * NSEQ) * rs + DMODEL + h * DH;
    const float* vbase = kbase + DMODEL;

    __shared__ __align__(16) float qs[4][2][DH];
    __shared__ __align__(16) __hip_bfloat16 w_lds[4][2][NSEQ];   // 16 KB

    qs[wid][0][lane] = qkv[(size_t)(b * NSEQ + iA) * rs + h * DH + lane];
    qs[wid][1][lane] = qkv[(size_t)(b * NSEQ + iB) * rs + h * DH + lane];
    __syncthreads();
    const float4* qA4 = reinterpret_cast<const float4*>(qs[wid][0]);
    const float4* qB4 = reinterpret_cast<const float4*>(qs[wid][1]);

    // ---- scores: shared K-row loads; A only needs chunks c<=7 ----
    float sA[16], sB[16];
#pragma unroll
    for (int c = 0; c < 16; ++c) {
        const int j0 = c << 6;
        const int j  = lane + j0;
        float vA = -1e30f, vB = -1e30f;
        if (j0 <= iB) {                          // wave-uniform
            const float4* krow = reinterpret_cast<const float4*>(kbase + (size_t)j * rs);
            if (j0 <= iA) {                      // wave-uniform: dual dot
                float aA = 0.f, aB = 0.f;
#pragma unroll
                for (int d4 = 0; d4 < 16; ++d4) {
                    const float4 kv = krow[d4];
                    const float4 qa = qA4[d4];
                    const float4 qb = qB4[d4];
                    aA = fmaf(qa.x, kv.x, aA); aA = fmaf(qa.y, kv.y, aA);
                    aA = fmaf(qa.z, kv.z, aA); aA = fmaf(qa.w, kv.w, aA);
                    aB = fmaf(qb.x, kv.x, aB); aB = fmaf(qb.y, kv.y, aB);
                    aB = fmaf(qb.z, kv.z, aB); aB = fmaf(qb.w, kv.w, aB);
                }
                if (j <= iA) vA = aA * SCALE;
                if (j <= iB) vB = aB * SCALE;
            } else {                             // B-only dot
                float aB = 0.f;
#pragma unroll
                for (int d4 = 0; d4 < 16; ++d4) {
                    const float4 kv = krow[d4];
                    const float4 qb = qB4[d4];
                    aB = fmaf(qb.x, kv.x, aB); aB = fmaf(qb.y, kv.y, aB);
                    aB = fmaf(qb.z, kv.z, aB); aB = fmaf(qb.w, kv.w, aB);
                }
                if (j <= iB) vB = aB * SCALE;
            }
        }
        sA[c] = vA; sB[c] = vB;
    }

    // ---- lambda init (dual) ----
    float mA = -1e30f, mB = -1e30f;
#pragma unroll
    for (int c = 0; c < 16; ++c) { mA = fmaxf(mA, sA[c]); mB = fmaxf(mB, sB[c]); }
#pragma unroll
    for (int off = 32; off; off >>= 1) {
        mA = fmaxf(mA, __shfl_xor(mA, off));
        mB = fmaxf(mB, __shfl_xor(mB, off));
    }
    float lamA = mA + 1.0f, lamB = mB + 1.0f;

    // ---- Newton (dual, unmasked: invalid entries contribute ~1e-30) ----
    for (int it = 0; it < NUM_ITER; ++it) {
        float fA = 0.f, fpA = 0.f, fB = 0.f, fpB = 0.f;
#pragma unroll
        for (int c = 0; c < 16; ++c) {
            const float dA   = fmaxf(lamA - sA[c], EPS);
            const float invA = __builtin_amdgcn_rcpf(dA);
            fA += invA; fpA = fmaf(invA, invA, fpA);
            const float dB   = fmaxf(lamB - sB[c], EPS);
            const float invB = __builtin_amdgcn_rcpf(dB);
            fB += invB; fpB = fmaf(invB, invB, fpB);
        }
#pragma unroll
        for (int off = 32; off; off >>= 1) {
            fA += __shfl_xor(fA, off); fpA += __shfl_xor(fpA, off);
            fB += __shfl_xor(fB, off); fpB += __shfl_xor(fpB, off);
        }
        lamA += (fA - 1.0f) / fpA;
        lamB += (fB - 1.0f) / fpB;
    }

    // ---- final weights + normalizers ----
    float wA[16], wB[16], swA = 0.f, swB = 0.f;
#pragma unroll
    for (int c = 0; c < 16; ++c) {
        wA[c] = __builtin_amdgcn_rcpf(fmaxf(lamA - sA[c], EPS)); swA += wA[c];
        wB[c] = __builtin_amdgcn_rcpf(fmaxf(lamB - sB[c], EPS)); swB += wB[c];
    }
#pragma unroll
    for (int off = 32; off; off >>= 1) {
        swA += __shfl_xor(swA, off);
        swB += __shfl_xor(swB, off);
    }
    const float invswA = __builtin_amdgcn_rcpf(swA);
    const float invswB = __builtin_amdgcn_rcpf(swB);

    // ---- stage normalized weights (bf16) to this wave's LDS rows ----
#pragma unroll
    for (int c = 0; c < 16; ++c) {
        const int j = lane + (c << 6);
        w_lds[wid][0][j] = __float2bfloat16(wA[c] * invswA);
        w_lds[wid][1][j] = __float2bfloat16(wB[c] * invswB);
    }
    // same-wave LDS RAW; compiler inserts lgkmcnt wait.

    // ---- PV: lane owns dim=lane.  Shared V loads on common prefix [0..iA].
    const float* __restrict__ vcol = vbase + lane;
    const __hip_bfloat16* __restrict__ wrA = w_lds[wid][0];
    const __hip_bfloat16* __restrict__ wrB = w_lds[wid][1];
    const int nA = iA + 1, nB = iB + 1;
    float aA0 = 0.f, aA1 = 0.f, aB0 = 0.f, aB1 = 0.f;
    int j = 0;
    for (; j + 8 <= nA; j += 8) {                 // j % 8 == 0 here
        const uint4 wa = *reinterpret_cast<const uint4*>(&wrA[j]);
        const uint4 wb = *reinterpret_cast<const uint4*>(&wrB[j]);
        const float v0 = vcol[(size_t)(j + 0) * rs];
        const float v1 = vcol[(size_t)(j + 1) * rs];
        const float v2 = vcol[(size_t)(j + 2) * rs];
        const float v3 = vcol[(size_t)(j + 3) * rs];
        const float v4 = vcol[(size_t)(j + 4) * rs];
        const float v5 = vcol[(size_t)(j + 5) * rs];
        const float v6 = vcol[(size_t)(j + 6) * rs];
        const float v7 = vcol[(size_t)(j + 7) * rs];
        aA0 = fmaf(bf2f_u(wa.x & 0xffff), v0, aA0);
        aA1 = fmaf(bf2f_u(wa.x >> 16),    v1, aA1);
        aA0 = fmaf(bf2f_u(wa.y & 0xffff), v2, aA0);
        aA1 = fmaf(bf2f_u(wa.y >> 16),    v3, aA1);
        aA0 = fmaf(bf2f_u(wa.z & 0xffff), v4, aA0);
        aA1 = fmaf(bf2f_u(wa.z >> 16),    v5, aA1);
        aA0 = fmaf(bf2f_u(wa.w & 0xffff), v6, aA0);
        aA1 = fmaf(bf2f_u(wa.w >> 16),    v7, aA1);
        aB0 = fmaf(bf2f_u(wb.x & 0xffff), v0, aB0);
        aB1 = fmaf(bf2f_u(wb.x >> 16),    v1, aB1);
        aB0 = fmaf(bf2f_u(wb.y & 0xffff), v2, aB0);
        aB1 = fmaf(bf2f_u(wb.y >> 16),    v3, aB1);
        aB0 = fmaf(bf2f_u(wb.z & 0xffff), v4, aB0);
        aB1 = fmaf(bf2f_u(wb.z >> 16),    v5, aB1);
        aB0 = fmaf(bf2f_u(wb.w & 0xffff), v6, aB0);
        aB1 = fmaf(bf2f_u(wb.w >> 16),    v7, aB1);
    }
    for (; j < nA; ++j) {                          // dual tail
        const float v = vcol[(size_t)j * rs];
        aA0 = fmaf(bf2f_u(__builtin_bit_cast(unsigned short, wrA[j])), v, aA0);
        aB0 = fmaf(bf2f_u(__builtin_bit_cast(unsigned short, wrB[j])), v, aB0);
    }
    for (; j < nB && (j & 7); ++j) {               // align for vector B loop
        const float v = vcol[(size_t)j * rs];
        aB0 = fmaf(bf2f_u(__builtin_bit_cast(unsigned short, wrB[j])), v, aB0);
    }
    for (; j + 8 <= nB; j += 8) {
        const uint4 wb = *reinterpret_cast<const uint4*>(&wrB[j]);
        const float v0 = vcol[(size_t)(j + 0) * rs];
        const float v1 = vcol[(size_t)(j + 1) * rs];
        const float v2 = vcol[(size_t)(j + 2) * rs];
        const float v3 = vcol[(size_t)(j + 3) * rs];
        const float v4 = vcol[(size_t)(j + 4) * rs];
        const float v5 = vcol[(size_t)(j + 5) * rs];
        const float v6 = vcol[(size_t)(j + 6) * rs];
        const float v7 = vcol[(size_t)(j + 7) * rs];
        aB0 = fmaf(bf2f_u(wb.x & 0xffff), v0, aB0);
        aB1 = fmaf(bf2f_u(wb.x >> 16),    v1, aB1);
        aB0 = fmaf(bf2f_u(wb.y & 0xffff), v2, aB0);
        aB1 = fmaf(bf2f_u(wb.y >> 16),    v3, aB1);
        aB0 = fmaf(bf2f_u(wb.z & 0xffff), v4, aB0);
        aB1 = fmaf(bf2f_u(wb.z >> 16),    v5, aB1);
        aB0 = fmaf(bf2f_u(wb.w & 0xffff), v6, aB0);
        aB1 = fmaf(bf2f_u(wb.w >> 16),    v7, aB1);
    }
    for (; j < nB; ++j) {
        const float v = vcol[(size_t)j * rs];
        aB0 = fmaf(bf2f_u(__builtin_bit_cast(unsigned short, wrB[j])), v, aB0);
    }

    obf[((size_t)(b * NSEQ + iA) * HNUM + h) * DH + lane] = __float2bfloat16(aA0 + aA1);
    obf[((size_t)(b * NSEQ + iB) * HNUM + h) * DH + lane] = __float2bfloat16(aB0 + aB1);
}

extern "C" void kernel_launch(void* const* d_in, const int* in_sizes, int n_in,
                              void* d_out, int out_size, void* d_ws, size_t ws_size,
                              hipStream_t stream) {
    const float* x    = (const float*)d_in[0];   // [B,N,D]
    const float* Wqkv = (const float*)d_in[1];   // [3D, D]
    const float* Wo   = (const float*)d_in[2];   // [D, D]
    float* out = (float*)d_out;                  // [B,N,D] fp32

    const int M = BATCH * NSEQ;                  // 2048
    // ws layout
    char* ws = (char*)d_ws;
    float* qkv            = (float*)ws;                               // 25.2 MB
    ws += (size_t)M * 3 * DMODEL * sizeof(float);
    __hip_bfloat16* xbf   = (__hip_bfloat16*)ws; ws += (size_t)M * DMODEL * 2;
    __hip_bfloat16* wqbf  = (__hip_bfloat16*)ws; ws += (size_t)3 * DMODEL * DMODEL * 2;
    __hip_bfloat16* wobf  = (__hip_bfloat16*)ws; ws += (size_t)DMODEL * DMODEL * 2;
    __hip_bfloat16* obf   = (__hip_bfloat16*)ws; ws += (size_t)M * DMODEL * 2;

    dim3 blk(256);
    cast_f32_bf16<<<2048, blk, 0, stream>>>(x,    xbf,  M * DMODEL);
    cast_f32_bf16<<<2048, blk, 0, stream>>>(Wqkv, wqbf, 3 * DMODEL * DMODEL);
    cast_f32_bf16<<<1024, blk, 0, stream>>>(Wo,   wobf, DMODEL * DMODEL);

    dim3 g1(3 * DMODEL / 128, M / 128);          // (24,16)
    gemm_bt_bf16<<<g1, blk, 0, stream>>>(xbf, wqbf, qkv, M, 3 * DMODEL, DMODEL);

    dim3 ga(BATCH * HNUM * (NSEQ / 2) / 4);      // 4096 blocks
    stieltjes_attn_pair<<<ga, blk, 0, stream>>>(qkv, obf);

    dim3 g2(DMODEL / 128, M / 128);              // (8,16)
    gemm_bt_bf16<<<g2, blk, 0, stream>>>(obf, wobf, out, M, DMODEL, DMODEL);
}

// Round 5
// 174.882 us; speedup vs baseline: 6.1277x; 6.1277x over previous
//
#include <hip/hip_runtime.h>
#include <hip/hip_bf16.h>
#include <math.h>

#define HNUM 16
#define DH 64
#define NSEQ 1024
#define BATCH 2
#define DMODEL 1024
#define SCALE 0.125f
#define EPS 1e-6f
#define NUM_ITER 4
#define SPAD 1040   // u16 per S row (520 floats, %32 = 8 -> rows offset 8 banks)

// col swizzle for S: XOR bits 4-5 by (row>>2)&3 -> conflict-free frag writes
#define SSWZ(row, col) ((col) ^ ((((row) >> 2) & 3) << 4))

typedef float f32x4 __attribute__((ext_vector_type(4)));
typedef short bfrag __attribute__((ext_vector_type(8)));     // 8 bf16 = 4 VGPR
typedef unsigned int u32x4 __attribute__((ext_vector_type(4)));

__device__ inline float bf2f_u(unsigned int u) {
    return __builtin_bit_cast(float, u << 16);
}
__device__ inline unsigned short f2bf_u(float f) {
    return __builtin_bit_cast(unsigned short, __float2bfloat16(f));
}

// ---------------------------------------------------------------------------
// fp32 -> bf16 cast, float4-vectorized. n % 4 == 0.
// ---------------------------------------------------------------------------
__global__ __launch_bounds__(256) void cast_f32_bf16(const float* __restrict__ src,
                                                     __hip_bfloat16* __restrict__ dst,
                                                     int n) {
    const int stride = gridDim.x * blockDim.x;
    for (int idx = blockIdx.x * blockDim.x + threadIdx.x; idx * 4 < n; idx += stride) {
        const float4 v = *reinterpret_cast<const float4*>(&src[idx * 4]);
        ushort4 o;
        o.x = f2bf_u(v.x); o.y = f2bf_u(v.y); o.z = f2bf_u(v.z); o.w = f2bf_u(v.w);
        *reinterpret_cast<ushort4*>(&dst[idx * 4]) = o;
    }
}

// ---------------------------------------------------------------------------
// C[M,Nc] = A[M,K] @ B[Nc,K]^T, A/B bf16 K-contiguous.  OUT_BF16 selects the
// C dtype (bf16 for qkv, fp32 for the final output).  128x128 tile, BK=64,
// 4 waves, 4x4 frags of mfma_f32_16x16x32_bf16.
// ---------------------------------------------------------------------------
template <bool OUT_BF16>
__global__ __launch_bounds__(256) void gemm_bt(const __hip_bfloat16* __restrict__ A,
                                               const __hip_bfloat16* __restrict__ B,
                                               void* __restrict__ Cv,
                                               int M, int Nc, int K) {
    __shared__ __align__(16) __hip_bfloat16 As[128][72];
    __shared__ __align__(16) __hip_bfloat16 Bs[128][72];
    const int tid  = threadIdx.x;
    const int l    = tid & 63;
    const int wave = tid >> 6;
    const int m0 = blockIdx.y * 128, n0 = blockIdx.x * 128;
    const int wr = (wave >> 1) * 64, wc = (wave & 1) * 64;
    const int lr = l & 15;
    const int lk = (l >> 4) * 8;

    f32x4 acc[4][4];
#pragma unroll
    for (int m = 0; m < 4; ++m)
#pragma unroll
        for (int n = 0; n < 4; ++n) acc[m][n] = (f32x4){0.f, 0.f, 0.f, 0.f};

    for (int k0 = 0; k0 < K; k0 += 64) {
#pragma unroll
        for (int p = 0; p < 4; ++p) {
            const int idx = tid + p * 256;
            const int r   = idx >> 3;
            const int ce  = (idx & 7) * 8;
            const uint4 av = *reinterpret_cast<const uint4*>(
                &A[(size_t)(m0 + r) * K + k0 + ce]);
            *reinterpret_cast<uint4*>(&As[r][ce]) = av;
            const uint4 bv = *reinterpret_cast<const uint4*>(
                &B[(size_t)(n0 + r) * K + k0 + ce]);
            *reinterpret_cast<uint4*>(&Bs[r][ce]) = bv;
        }
        __syncthreads();

#pragma unroll
        for (int kk = 0; kk < 64; kk += 32) {
            bfrag af[4], bfr[4];
#pragma unroll
            for (int m = 0; m < 4; ++m)
                af[m] = *reinterpret_cast<const bfrag*>(&As[wr + m * 16 + lr][kk + lk]);
#pragma unroll
            for (int n = 0; n < 4; ++n)
                bfr[n] = *reinterpret_cast<const bfrag*>(&Bs[wc + n * 16 + lr][kk + lk]);
#pragma unroll
            for (int m = 0; m < 4; ++m)
#pragma unroll
                for (int n = 0; n < 4; ++n)
                    acc[m][n] = __builtin_amdgcn_mfma_f32_16x16x32_bf16(
                        af[m], bfr[n], acc[m][n], 0, 0, 0);
        }
        __syncthreads();
    }

#pragma unroll
    for (int m = 0; m < 4; ++m) {
        const int row0 = m0 + wr + m * 16 + (l >> 4) * 4;
#pragma unroll
        for (int n = 0; n < 4; ++n) {
            const int col = n0 + wc + n * 16 + lr;
#pragma unroll
            for (int j = 0; j < 4; ++j) {
                if constexpr (OUT_BF16) {
                    ((__hip_bfloat16*)Cv)[(size_t)(row0 + j) * Nc + col] =
                        __float2bfloat16(acc[m][n][j]);
                } else {
                    ((float*)Cv)[(size_t)(row0 + j) * Nc + col] = acc[m][n][j];
                }
            }
        }
    }
}

// ---------------------------------------------------------------------------
// Vt[bh][d][n] = V[b,n,h,d] from qkvb rows.  64x64 LDS tile transpose.
// grid = B*H*(N/64) = 512, 256 thr.
// ---------------------------------------------------------------------------
__global__ __launch_bounds__(256) void transpose_v(const __hip_bfloat16* __restrict__ qkvb,
                                                   __hip_bfloat16* __restrict__ Vt) {
    const int bh = blockIdx.x >> 4;
    const int nc = blockIdx.x & 15;
    const int b = bh >> 4, h = bh & 15;
    __shared__ unsigned short tile[64][80];
    const int t = threadIdx.x;
    {
        const int r = t >> 2, cc = (t & 3) * 16;
        const size_t src = ((size_t)(b * NSEQ + nc * 64 + r)) * 3072 + 2048 + h * 64 + cc;
        const uint4 v0 = *reinterpret_cast<const uint4*>(&qkvb[src]);
        const uint4 v1 = *reinterpret_cast<const uint4*>(&qkvb[src + 8]);
        *reinterpret_cast<uint4*>(&tile[r][cc])     = v0;
        *reinterpret_cast<uint4*>(&tile[r][cc + 8]) = v1;
    }
    __syncthreads();
    {
        const int d = t >> 2, n2 = (t & 3) * 16;
        unsigned int e[16];
#pragma unroll
        for (int k = 0; k < 16; ++k) e[k] = tile[n2 + k][d];
        uint4 o0, o1;
        o0.x = e[0]  | (e[1]  << 16); o0.y = e[2]  | (e[3]  << 16);
        o0.z = e[4]  | (e[5]  << 16); o0.w = e[6]  | (e[7]  << 16);
        o1.x = e[8]  | (e[9]  << 16); o1.y = e[10] | (e[11] << 16);
        o1.z = e[12] | (e[13] << 16); o1.w = e[14] | (e[15] << 16);
        const size_t dst = ((size_t)(bh * 64 + d)) * 1024 + nc * 64 + n2;
        *reinterpret_cast<uint4*>(&Vt[dst])     = o0;
        *reinterpret_cast<uint4*>(&Vt[dst + 8]) = o1;
    }
}

// ---------------------------------------------------------------------------
// MFMA Stieltjes attention.  Block = (b,h, 32-row Q-tile), 8 waves.
// Phase 1: S[q][j] = (Q.K^T)*SCALE via mfma, bf16 in LDS (col-swizzled).
// Phase 2: Newton on lambda, 16 lanes/row, butterfly reduce; lam/isw -> LDS.
// Phase 3: O = P.V via mfma; P computed on the fly from S,lam,isw; B = Vt.
// ---------------------------------------------------------------------------
__global__ __launch_bounds__(512) void attn_mfma(const __hip_bfloat16* __restrict__ qkvb,
                                                 const __hip_bfloat16* __restrict__ Vt,
                                                 __hip_bfloat16* __restrict__ obf) {
    const int tid  = threadIdx.x;
    const int lane = tid & 63;
    const int wave = tid >> 6;               // 0..7
    const int qt = blockIdx.x & 31;
    const int bh = blockIdx.x >> 5;
    const int b = bh >> 4, h = bh & 15;
    const int r0 = qt * 32;

    __shared__ __align__(16) unsigned short S[32][SPAD];   // bf16 scores
    __shared__ __align__(16) unsigned short Qs[32][80];    // bf16 Q tile
    __shared__ float lamS[32], iswS[32];

    const size_t qbase = (size_t)(b * NSEQ) * 3072;
    const int lr  = lane & 15;
    const int lk8 = (lane >> 4) * 8;

    // ---- stage Q tile (32 x 64 bf16) ----
    if (tid < 256) {
        const int r = tid >> 3, c = (tid & 7) * 8;
        const uint4 v = *reinterpret_cast<const uint4*>(
            &qkvb[qbase + (size_t)(r0 + r) * 3072 + h * 64 + c]);
        *reinterpret_cast<uint4*>(&Qs[r][c]) = v;
    }
    __syncthreads();

    // ---- phase 1: QK^T ----
    const __hip_bfloat16* kglob = qkvb + qbase + 1024 + h * 64;
    const int ntask = 4 * qt + 4;            // (2 qsub) x (2qt+2 col tiles)
    for (int task = wave; task < ntask; task += 8) {
        const int qsub = task & 1, jt = task >> 1;
        const int jrow = jt * 16 + lr;
        const bfrag a0 = *reinterpret_cast<const bfrag*>(&Qs[qsub * 16 + lr][lk8]);
        const bfrag a1 = *reinterpret_cast<const bfrag*>(&Qs[qsub * 16 + lr][32 + lk8]);
        const bfrag b0 = *reinterpret_cast<const bfrag*>(&kglob[(size_t)jrow * 3072 + lk8]);
        const bfrag b1 = *reinterpret_cast<const bfrag*>(&kglob[(size_t)jrow * 3072 + 32 + lk8]);
        f32x4 c = (f32x4){0.f, 0.f, 0.f, 0.f};
        c = __builtin_amdgcn_mfma_f32_16x16x32_bf16(a0, b0, c, 0, 0, 0);
        c = __builtin_amdgcn_mfma_f32_16x16x32_bf16(a1, b1, c, 0, 0, 0);
#pragma unroll
        for (int j = 0; j < 4; ++j) {
            const int row = qsub * 16 + (lane >> 4) * 4 + j;
            const int col = jt * 16 + lr;
            S[row][SSWZ(row, col)] = f2bf_u(c[j] * SCALE);
        }
    }
    __syncthreads();

    // ---- phase 2: Newton (16 lanes per row) ----
    {
        const int rw    = wave * 4 + (lane >> 4);      // row 0..31
        const int i_abs = r0 + rw;
        const int c0    = lane & 15;
        const int ncols = i_abs + 1;
        const int ntmax = (r0 + wave * 4 + 3) / 16 + 1;  // wave-uniform
        const unsigned short* Srow = S[rw];
        const int fsw = ((rw >> 2) & 3) << 4;

        float mx = -1e30f;
        for (int t = 0; t < ntmax; ++t) {
            const int c = c0 + t * 16;
            const float s = bf2f_u(Srow[c ^ fsw]);
            mx = (c < ncols) ? fmaxf(mx, s) : mx;
        }
#pragma unroll
        for (int off = 1; off <= 8; off <<= 1) mx = fmaxf(mx, __shfl_xor(mx, off));
        float lam = mx + 1.0f;

        for (int it = 0; it < NUM_ITER; ++it) {
            float f = 0.f, fp = 0.f;
            for (int t = 0; t < ntmax; ++t) {
                const int c = c0 + t * 16;
                const float s = bf2f_u(Srow[c ^ fsw]);
                float inv = __builtin_amdgcn_rcpf(fmaxf(lam - s, EPS));
                inv = (c < ncols) ? inv : 0.f;
                f += inv; fp = fmaf(inv, inv, fp);
            }
#pragma unroll
            for (int off = 1; off <= 8; off <<= 1) {
                f  += __shfl_xor(f, off);
                fp += __shfl_xor(fp, off);
            }
            lam += (f - 1.0f) / fp;
        }

        float sw = 0.f;
        for (int t = 0; t < ntmax; ++t) {
            const int c = c0 + t * 16;
            const float s = bf2f_u(Srow[c ^ fsw]);
            const float inv = __builtin_amdgcn_rcpf(fmaxf(lam - s, EPS));
            sw += (c < ncols) ? inv : 0.f;
        }
#pragma unroll
        for (int off = 1; off <= 8; off <<= 1) sw += __shfl_xor(sw, off);
        if (c0 == 0) {
            lamS[rw] = lam;
            iswS[rw] = __builtin_amdgcn_rcpf(sw);
        }
    }
    __syncthreads();

    // ---- phase 3: PV.  wave -> (qsub, dt); out tile 16q x 16d ----
    {
        const int qsub = wave & 1, dt = wave >> 1;
        const int qrow = qsub * 16 + lr;               // A-frag row
        const int iq   = r0 + qrow;
        const float lamq = lamS[qrow];
        const float iswq = iswS[qrow];
        const int fsw = ((qrow >> 2) & 3) << 4;
        const __hip_bfloat16* vtrow = Vt + ((size_t)(bh * 64 + dt * 16 + lr)) * 1024;

        f32x4 acc = (f32x4){0.f, 0.f, 0.f, 0.f};
        for (int j0 = 0; j0 <= r0; j0 += 32) {
            const int jb = j0 + lk8;                    // this lane's 8-col slice
            const u32x4 sv = *reinterpret_cast<const u32x4*>(&S[qrow][jb ^ fsw]);
            unsigned int pw0, pw1, pw2, pw3;
            {
                const float s0 = bf2f_u(sv.x & 0xffffu), s1 = bf2f_u(sv.x >> 16);
                const float w0 = (jb + 0 <= iq) ? __builtin_amdgcn_rcpf(fmaxf(lamq - s0, EPS)) * iswq : 0.f;
                const float w1 = (jb + 1 <= iq) ? __builtin_amdgcn_rcpf(fmaxf(lamq - s1, EPS)) * iswq : 0.f;
                pw0 = (unsigned)f2bf_u(w0) | ((unsigned)f2bf_u(w1) << 16);
            }
            {
                const float s0 = bf2f_u(sv.y & 0xffffu), s1 = bf2f_u(sv.y >> 16);
                const float w0 = (jb + 2 <= iq) ? __builtin_amdgcn_rcpf(fmaxf(lamq - s0, EPS)) * iswq : 0.f;
                const float w1 = (jb + 3 <= iq) ? __builtin_amdgcn_rcpf(fmaxf(lamq - s1, EPS)) * iswq : 0.f;
                pw1 = (unsigned)f2bf_u(w0) | ((unsigned)f2bf_u(w1) << 16);
            }
            {
                const float s0 = bf2f_u(sv.z & 0xffffu), s1 = bf2f_u(sv.z >> 16);
                const float w0 = (jb + 4 <= iq) ? __builtin_amdgcn_rcpf(fmaxf(lamq - s0, EPS)) * iswq : 0.f;
                const float w1 = (jb + 5 <= iq) ? __builtin_amdgcn_rcpf(fmaxf(lamq - s1, EPS)) * iswq : 0.f;
                pw2 = (unsigned)f2bf_u(w0) | ((unsigned)f2bf_u(w1) << 16);
            }
            {
                const float s0 = bf2f_u(sv.w & 0xffffu), s1 = bf2f_u(sv.w >> 16);
                const float w0 = (jb + 6 <= iq) ? __builtin_amdgcn_rcpf(fmaxf(lamq - s0, EPS)) * iswq : 0.f;
                const float w1 = (jb + 7 <= iq) ? __builtin_amdgcn_rcpf(fmaxf(lamq - s1, EPS)) * iswq : 0.f;
                pw3 = (unsigned)f2bf_u(w0) | ((unsigned)f2bf_u(w1) << 16);
            }
            const u32x4 pwv = (u32x4){pw0, pw1, pw2, pw3};
            const bfrag pa = __builtin_bit_cast(bfrag, pwv);
            const bfrag pb = *reinterpret_cast<const bfrag*>(&vtrow[jb]);
            acc = __builtin_amdgcn_mfma_f32_16x16x32_bf16(pa, pb, acc, 0, 0, 0);
        }

#pragma unroll
        for (int j = 0; j < 4; ++j) {
            const int row = qsub * 16 + (lane >> 4) * 4 + j;
            obf[(size_t)(b * NSEQ + r0 + row) * 1024 + h * 64 + dt * 16 + lr] =
                __float2bfloat16(acc[j]);
        }
    }
}

extern "C" void kernel_launch(void* const* d_in, const int* in_sizes, int n_in,
                              void* d_out, int out_size, void* d_ws, size_t ws_size,
                              hipStream_t stream) {
    const float* x    = (const float*)d_in[0];   // [B,N,D]
    const float* Wqkv = (const float*)d_in[1];   // [3D, D]
    const float* Wo   = (const float*)d_in[2];   // [D, D]
    float* out = (float*)d_out;                  // [B,N,D] fp32

    const int M = BATCH * NSEQ;                  // 2048
    char* ws = (char*)d_ws;
    __hip_bfloat16* xbf  = (__hip_bfloat16*)ws; ws += (size_t)M * DMODEL * 2;
    __hip_bfloat16* wqbf = (__hip_bfloat16*)ws; ws += (size_t)3 * DMODEL * DMODEL * 2;
    __hip_bfloat16* wobf = (__hip_bfloat16*)ws; ws += (size_t)DMODEL * DMODEL * 2;
    __hip_bfloat16* qkvb = (__hip_bfloat16*)ws; ws += (size_t)M * 3 * DMODEL * 2;
    __hip_bfloat16* Vt   = (__hip_bfloat16*)ws; ws += (size_t)BATCH * HNUM * DH * NSEQ * 2;
    __hip_bfloat16* obf  = (__hip_bfloat16*)ws; ws += (size_t)M * DMODEL * 2;

    dim3 blk(256);
    cast_f32_bf16<<<2048, blk, 0, stream>>>(x,    xbf,  M * DMODEL);
    cast_f32_bf16<<<2048, blk, 0, stream>>>(Wqkv, wqbf, 3 * DMODEL * DMODEL);
    cast_f32_bf16<<<1024, blk, 0, stream>>>(Wo,   wobf, DMODEL * DMODEL);

    dim3 g1(3 * DMODEL / 128, M / 128);          // (24,16)
    gemm_bt<true><<<g1, blk, 0, stream>>>(xbf, wqbf, qkvb, M, 3 * DMODEL, DMODEL);

    transpose_v<<<512, blk, 0, stream>>>(qkvb, Vt);

    attn_mfma<<<1024, dim3(512), 0, stream>>>(qkvb, Vt, obf);

    dim3 g2(DMODEL / 128, M / 128);              // (8,16)
    gemm_bt<false><<<g2, blk, 0, stream>>>(obf, wobf, out, M, DMODEL, DMODEL);
}

// Round 6
// 153.821 us; speedup vs baseline: 6.9667x; 1.1369x over previous
//
#include <hip/hip_runtime.h>
#include <hip/hip_bf16.h>
#include <math.h>

#define HNUM 16
#define DH 64
#define NSEQ 1024
#define BATCH 2
#define DMODEL 1024
#define SCALE 0.125f
#define EPS 1e-6f
#define NUM_ITER 4
#define SPAD 1032   // u16/row: 2064 B = 129*16 -> odd 16B-slot stride, frag reads conflict-free

typedef float f32x4 __attribute__((ext_vector_type(4)));
typedef short bfrag __attribute__((ext_vector_type(8)));     // 8 bf16 = 4 VGPR
typedef unsigned int u32x4 __attribute__((ext_vector_type(4)));

__device__ inline float bf2f_u(unsigned int u) {
    return __builtin_bit_cast(float, u << 16);
}
__device__ inline unsigned short f2bf_u(float f) {
    return __builtin_bit_cast(unsigned short, __float2bfloat16(f));
}

// ---------------------------------------------------------------------------
// fp32 -> bf16 cast, float4-vectorized. n % 4 == 0.
// ---------------------------------------------------------------------------
__global__ __launch_bounds__(256) void cast_f32_bf16(const float* __restrict__ src,
                                                     __hip_bfloat16* __restrict__ dst,
                                                     int n) {
    const int stride = gridDim.x * blockDim.x;
    for (int idx = blockIdx.x * blockDim.x + threadIdx.x; idx * 4 < n; idx += stride) {
        const float4 v = *reinterpret_cast<const float4*>(&src[idx * 4]);
        ushort4 o;
        o.x = f2bf_u(v.x); o.y = f2bf_u(v.y); o.z = f2bf_u(v.z); o.w = f2bf_u(v.w);
        *reinterpret_cast<ushort4*>(&dst[idx * 4]) = o;
    }
}

// ---------------------------------------------------------------------------
// C[M,Nc] = A[M,K] @ B[Nc,K]^T, A/B bf16 K-contiguous.  128x128 tile, BK=64,
// 4 waves, 4x4 frags of mfma_f32_16x16x32_bf16.
// ---------------------------------------------------------------------------
template <bool OUT_BF16>
__global__ __launch_bounds__(256) void gemm_bt(const __hip_bfloat16* __restrict__ A,
                                               const __hip_bfloat16* __restrict__ B,
                                               void* __restrict__ Cv,
                                               int M, int Nc, int K) {
    __shared__ __align__(16) __hip_bfloat16 As[128][72];
    __shared__ __align__(16) __hip_bfloat16 Bs[128][72];
    const int tid  = threadIdx.x;
    const int l    = tid & 63;
    const int wave = tid >> 6;
    const int m0 = blockIdx.y * 128, n0 = blockIdx.x * 128;
    const int wr = (wave >> 1) * 64, wc = (wave & 1) * 64;
    const int lr = l & 15;
    const int lk = (l >> 4) * 8;

    f32x4 acc[4][4];
#pragma unroll
    for (int m = 0; m < 4; ++m)
#pragma unroll
        for (int n = 0; n < 4; ++n) acc[m][n] = (f32x4){0.f, 0.f, 0.f, 0.f};

    for (int k0 = 0; k0 < K; k0 += 64) {
#pragma unroll
        for (int p = 0; p < 4; ++p) {
            const int idx = tid + p * 256;
            const int r   = idx >> 3;
            const int ce  = (idx & 7) * 8;
            const uint4 av = *reinterpret_cast<const uint4*>(
                &A[(size_t)(m0 + r) * K + k0 + ce]);
            *reinterpret_cast<uint4*>(&As[r][ce]) = av;
            const uint4 bv = *reinterpret_cast<const uint4*>(
                &B[(size_t)(n0 + r) * K + k0 + ce]);
            *reinterpret_cast<uint4*>(&Bs[r][ce]) = bv;
        }
        __syncthreads();

#pragma unroll
        for (int kk = 0; kk < 64; kk += 32) {
            bfrag af[4], bfr[4];
#pragma unroll
            for (int m = 0; m < 4; ++m)
                af[m] = *reinterpret_cast<const bfrag*>(&As[wr + m * 16 + lr][kk + lk]);
#pragma unroll
            for (int n = 0; n < 4; ++n)
                bfr[n] = *reinterpret_cast<const bfrag*>(&Bs[wc + n * 16 + lr][kk + lk]);
#pragma unroll
            for (int m = 0; m < 4; ++m)
#pragma unroll
                for (int n = 0; n < 4; ++n)
                    acc[m][n] = __builtin_amdgcn_mfma_f32_16x16x32_bf16(
                        af[m], bfr[n], acc[m][n], 0, 0, 0);
        }
        __syncthreads();
    }

#pragma unroll
    for (int m = 0; m < 4; ++m) {
        const int row0 = m0 + wr + m * 16 + (l >> 4) * 4;
#pragma unroll
        for (int n = 0; n < 4; ++n) {
            const int col = n0 + wc + n * 16 + lr;
#pragma unroll
            for (int j = 0; j < 4; ++j) {
                if constexpr (OUT_BF16) {
                    ((__hip_bfloat16*)Cv)[(size_t)(row0 + j) * Nc + col] =
                        __float2bfloat16(acc[m][n][j]);
                } else {
                    ((float*)Cv)[(size_t)(row0 + j) * Nc + col] = acc[m][n][j];
                }
            }
        }
    }
}

// ---------------------------------------------------------------------------
// Vt[bh][d][n] = V[b,n,h,d] from qkvb rows.  64x64 LDS tile transpose.
// ---------------------------------------------------------------------------
__global__ __launch_bounds__(256) void transpose_v(const __hip_bfloat16* __restrict__ qkvb,
                                                   __hip_bfloat16* __restrict__ Vt) {
    const int bh = blockIdx.x >> 4;
    const int nc = blockIdx.x & 15;
    const int b = bh >> 4, h = bh & 15;
    __shared__ unsigned short tile[64][80];
    const int t = threadIdx.x;
    {
        const int r = t >> 2, cc = (t & 3) * 16;
        const size_t src = ((size_t)(b * NSEQ + nc * 64 + r)) * 3072 + 2048 + h * 64 + cc;
        const uint4 v0 = *reinterpret_cast<const uint4*>(&qkvb[src]);
        const uint4 v1 = *reinterpret_cast<const uint4*>(&qkvb[src + 8]);
        *reinterpret_cast<uint4*>(&tile[r][cc])     = v0;
        *reinterpret_cast<uint4*>(&tile[r][cc + 8]) = v1;
    }
    __syncthreads();
    {
        const int d = t >> 2, n2 = (t & 3) * 16;
        unsigned int e[16];
#pragma unroll
        for (int k = 0; k < 16; ++k) e[k] = tile[n2 + k][d];
        uint4 o0, o1;
        o0.x = e[0]  | (e[1]  << 16); o0.y = e[2]  | (e[3]  << 16);
        o0.z = e[4]  | (e[5]  << 16); o0.w = e[6]  | (e[7]  << 16);
        o1.x = e[8]  | (e[9]  << 16); o1.y = e[10] | (e[11] << 16);
        o1.z = e[12] | (e[13] << 16); o1.w = e[14] | (e[15] << 16);
        const size_t dst = ((size_t)(bh * 64 + d)) * 1024 + nc * 64 + n2;
        *reinterpret_cast<uint4*>(&Vt[dst])     = o0;
        *reinterpret_cast<uint4*>(&Vt[dst + 8]) = o1;
    }
}

// ---------------------------------------------------------------------------
// MFMA Stieltjes attention.  Block = (b,h, 32-row Q-tile), 8 waves.
// P1: S = (Q.K^T)*SCALE via mfma -> bf16 LDS (padded rows, no swizzle).
// P2: one WAVE per row; row loaded ONCE into 16 reg floats; Newton in regs.
// P2.5: S -> P in place (normalized masked bf16 weights), vectorized b128.
// P3: O = P.V -- pure MFMA (LDS P-frags + global Vt-frags).
// ---------------------------------------------------------------------------
__global__ __launch_bounds__(512) void attn_mfma(const __hip_bfloat16* __restrict__ qkvb,
                                                 const __hip_bfloat16* __restrict__ Vt,
                                                 __hip_bfloat16* __restrict__ obf) {
    const int tid  = threadIdx.x;
    const int lane = tid & 63;
    const int wave = tid >> 6;               // 0..7
    const int qt = blockIdx.x & 31;
    const int bh = blockIdx.x >> 5;
    const int b = bh >> 4, h = bh & 15;
    const int r0 = qt * 32;

    __shared__ __align__(16) unsigned short S[32][SPAD];   // scores -> weights
    __shared__ __align__(16) unsigned short Qs[32][72];    // bf16 Q tile
    __shared__ float lamS[32], iswS[32];

    const size_t qbase = (size_t)(b * NSEQ) * 3072;
    const int lr  = lane & 15;
    const int lk8 = (lane >> 4) * 8;

    // ---- stage Q tile (32 x 64 bf16) ----
    if (tid < 256) {
        const int r = tid >> 3, c = (tid & 7) * 8;
        const uint4 v = *reinterpret_cast<const uint4*>(
            &qkvb[qbase + (size_t)(r0 + r) * 3072 + h * 64 + c]);
        *reinterpret_cast<uint4*>(&Qs[r][c]) = v;
    }
    __syncthreads();

    // ---- phase 1: QK^T ----
    const __hip_bfloat16* kglob = qkvb + qbase + 1024 + h * 64;
    const int ntask = 4 * qt + 4;            // (2 qsub) x (2qt+2 col tiles)
    for (int task = wave; task < ntask; task += 8) {
        const int qsub = task & 1, jt = task >> 1;
        const int jrow = jt * 16 + lr;
        const bfrag a0 = *reinterpret_cast<const bfrag*>(&Qs[qsub * 16 + lr][lk8]);
        const bfrag a1 = *reinterpret_cast<const bfrag*>(&Qs[qsub * 16 + lr][32 + lk8]);
        const bfrag b0 = *reinterpret_cast<const bfrag*>(&kglob[(size_t)jrow * 3072 + lk8]);
        const bfrag b1 = *reinterpret_cast<const bfrag*>(&kglob[(size_t)jrow * 3072 + 32 + lk8]);
        f32x4 c = (f32x4){0.f, 0.f, 0.f, 0.f};
        c = __builtin_amdgcn_mfma_f32_16x16x32_bf16(a0, b0, c, 0, 0, 0);
        c = __builtin_amdgcn_mfma_f32_16x16x32_bf16(a1, b1, c, 0, 0, 0);
#pragma unroll
        for (int j = 0; j < 4; ++j) {
            const int row = qsub * 16 + (lane >> 4) * 4 + j;
            S[row][jt * 16 + lr] = f2bf_u(c[j] * SCALE);
        }
    }
    __syncthreads();

    // ---- phase 2: Newton, one wave per row, scores register-resident ----
#pragma unroll 1
    for (int rr = 0; rr < 4; ++rr) {
        const int row   = wave * 4 + rr;
        const int ncols = r0 + row + 1;
        const unsigned short* Srow = S[row];

        float sv[16];
#pragma unroll
        for (int t = 0; t < 8; ++t) {
            const int c = lane * 2 + t * 128;
            const unsigned int u = *reinterpret_cast<const unsigned int*>(&Srow[c]);
            sv[2 * t]     = (c     < ncols) ? bf2f_u(u & 0xffffu) : -1e30f;
            sv[2 * t + 1] = (c + 1 < ncols) ? bf2f_u(u >> 16)     : -1e30f;
        }

        float mx = sv[0];
#pragma unroll
        for (int e = 1; e < 16; ++e) mx = fmaxf(mx, sv[e]);
#pragma unroll
        for (int off = 32; off; off >>= 1) mx = fmaxf(mx, __shfl_xor(mx, off));
        float lam = mx + 1.0f;

        for (int it = 0; it < NUM_ITER; ++it) {
            float f = 0.f, fp = 0.f;
#pragma unroll
            for (int e = 0; e < 16; ++e) {
                const float inv = __builtin_amdgcn_rcpf(fmaxf(lam - sv[e], EPS));
                f += inv; fp = fmaf(inv, inv, fp);
            }
#pragma unroll
            for (int off = 32; off; off >>= 1) {
                f  += __shfl_xor(f, off);
                fp += __shfl_xor(fp, off);
            }
            lam += (f - 1.0f) / fp;
        }

        float sw = 0.f;
#pragma unroll
        for (int e = 0; e < 16; ++e)
            sw += __builtin_amdgcn_rcpf(fmaxf(lam - sv[e], EPS));
#pragma unroll
        for (int off = 32; off; off >>= 1) sw += __shfl_xor(sw, off);

        if (lane == 0) {
            lamS[row] = lam;
            iswS[row] = __builtin_amdgcn_rcpf(sw);
        }
    }
    __syncthreads();

    // ---- phase 2.5: S -> P in place (masked, normalized, bf16) ----
    {
        // 32 rows x 128 u32x4-units; 512 threads x 8 units each
#pragma unroll
        for (int it = 0; it < 8; ++it) {
            const int u   = tid + it * 512;
            const int row = u >> 7;
            const int c0  = (u & 127) * 8;            // elem col
            const int iq  = r0 + row;
            const float lam = lamS[row];
            const float isw = iswS[row];
            u32x4 sv = *reinterpret_cast<const u32x4*>(&S[row][c0]);
            unsigned int po[4];
#pragma unroll
            for (int k = 0; k < 4; ++k) {
                const float s0 = bf2f_u(sv[k] & 0xffffu);
                const float s1 = bf2f_u(sv[k] >> 16);
                const float w0 = (c0 + 2 * k     <= iq)
                    ? __builtin_amdgcn_rcpf(fmaxf(lam - s0, EPS)) * isw : 0.f;
                const float w1 = (c0 + 2 * k + 1 <= iq)
                    ? __builtin_amdgcn_rcpf(fmaxf(lam - s1, EPS)) * isw : 0.f;
                po[k] = (unsigned)f2bf_u(w0) | ((unsigned)f2bf_u(w1) << 16);
            }
            *reinterpret_cast<u32x4*>(&S[row][c0]) = (u32x4){po[0], po[1], po[2], po[3]};
        }
    }
    __syncthreads();

    // ---- phase 3: O = P.V, pure MFMA ----
    {
        const int qsub = wave & 1, dt = wave >> 1;
        const int qrow = qsub * 16 + lr;
        const __hip_bfloat16* vtrow = Vt + ((size_t)(bh * 64 + dt * 16 + lr)) * 1024;

        f32x4 acc = (f32x4){0.f, 0.f, 0.f, 0.f};
        for (int j0 = 0; j0 <= r0; j0 += 32) {
            const bfrag pa = *reinterpret_cast<const bfrag*>(&S[qrow][j0 + lk8]);
            const bfrag pb = *reinterpret_cast<const bfrag*>(&vtrow[j0 + lk8]);
            acc = __builtin_amdgcn_mfma_f32_16x16x32_bf16(pa, pb, acc, 0, 0, 0);
        }

#pragma unroll
        for (int j = 0; j < 4; ++j) {
            const int row = qsub * 16 + (lane >> 4) * 4 + j;
            obf[(size_t)(b * NSEQ + r0 + row) * 1024 + h * 64 + dt * 16 + lr] =
                __float2bfloat16(acc[j]);
        }
    }
}

extern "C" void kernel_launch(void* const* d_in, const int* in_sizes, int n_in,
                              void* d_out, int out_size, void* d_ws, size_t ws_size,
                              hipStream_t stream) {
    const float* x    = (const float*)d_in[0];   // [B,N,D]
    const float* Wqkv = (const float*)d_in[1];   // [3D, D]
    const float* Wo   = (const float*)d_in[2];   // [D, D]
    float* out = (float*)d_out;                  // [B,N,D] fp32

    const int M = BATCH * NSEQ;                  // 2048
    char* ws = (char*)d_ws;
    __hip_bfloat16* xbf  = (__hip_bfloat16*)ws; ws += (size_t)M * DMODEL * 2;
    __hip_bfloat16* wqbf = (__hip_bfloat16*)ws; ws += (size_t)3 * DMODEL * DMODEL * 2;
    __hip_bfloat16* wobf = (__hip_bfloat16*)ws; ws += (size_t)DMODEL * DMODEL * 2;
    __hip_bfloat16* qkvb = (__hip_bfloat16*)ws; ws += (size_t)M * 3 * DMODEL * 2;
    __hip_bfloat16* Vt   = (__hip_bfloat16*)ws; ws += (size_t)BATCH * HNUM * DH * NSEQ * 2;
    __hip_bfloat16* obf  = (__hip_bfloat16*)ws; ws += (size_t)M * DMODEL * 2;

    dim3 blk(256);
    cast_f32_bf16<<<2048, blk, 0, stream>>>(x,    xbf,  M * DMODEL);
    cast_f32_bf16<<<2048, blk, 0, stream>>>(Wqkv, wqbf, 3 * DMODEL * DMODEL);
    cast_f32_bf16<<<1024, blk, 0, stream>>>(Wo,   wobf, DMODEL * DMODEL);

    dim3 g1(3 * DMODEL / 128, M / 128);          // (24,16)
    gemm_bt<true><<<g1, blk, 0, stream>>>(xbf, wqbf, qkvb, M, 3 * DMODEL, DMODEL);

    transpose_v<<<512, blk, 0, stream>>>(qkvb, Vt);

    attn_mfma<<<1024, dim3(512), 0, stream>>>(qkvb, Vt, obf);

    dim3 g2(DMODEL / 128, M / 128);              // (8,16)
    gemm_bt<false><<<g2, blk, 0, stream>>>(obf, wobf, out, M, DMODEL, DMODEL);
}

// Round 7
// 127.757 us; speedup vs baseline: 8.3881x; 1.2040x over previous
//
#include <hip/hip_runtime.h>
#include <hip/hip_bf16.h>
#include <math.h>

#define HNUM 16
#define DH 64
#define NSEQ 1024
#define BATCH 2
#define DMODEL 1024
#define SCALE 0.125f
#define EPS 1e-6f
#define NUM_ITER 4
#define SPAD 1032   // u16/row: 2064 B -> odd 16B-slot stride, frag reads conflict-free

typedef float f32x4 __attribute__((ext_vector_type(4)));
typedef short bfrag __attribute__((ext_vector_type(8)));     // 8 bf16 = 4 VGPR
typedef unsigned int u32x4 __attribute__((ext_vector_type(4)));

__device__ inline float bf2f_u(unsigned int u) {
    return __builtin_bit_cast(float, u << 16);
}
__device__ inline unsigned short f2bf_u(float f) {
    return __builtin_bit_cast(unsigned short, __float2bfloat16(f));
}

// ---------------------------------------------------------------------------
// fp32 -> bf16 cast, float4-vectorized. n % 4 == 0.
// ---------------------------------------------------------------------------
__global__ __launch_bounds__(256) void cast_f32_bf16(const float* __restrict__ src,
                                                     __hip_bfloat16* __restrict__ dst,
                                                     int n) {
    const int stride = gridDim.x * blockDim.x;
    for (int idx = blockIdx.x * blockDim.x + threadIdx.x; idx * 4 < n; idx += stride) {
        const float4 v = *reinterpret_cast<const float4*>(&src[idx * 4]);
        ushort4 o;
        o.x = f2bf_u(v.x); o.y = f2bf_u(v.y); o.z = f2bf_u(v.z); o.w = f2bf_u(v.w);
        *reinterpret_cast<ushort4*>(&dst[idx * 4]) = o;
    }
}

// ---------------------------------------------------------------------------
// C[M,Nc] = A[M,K] @ B[Nc,K]^T, A/B bf16 K-contiguous.  128x128 tile, BK=64,
// 4 waves, 4x4 frags of mfma_f32_16x16x32_bf16.
// ---------------------------------------------------------------------------
template <bool OUT_BF16>
__global__ __launch_bounds__(256) void gemm_bt(const __hip_bfloat16* __restrict__ A,
                                               const __hip_bfloat16* __restrict__ B,
                                               void* __restrict__ Cv,
                                               int M, int Nc, int K) {
    __shared__ __align__(16) __hip_bfloat16 As[128][72];
    __shared__ __align__(16) __hip_bfloat16 Bs[128][72];
    const int tid  = threadIdx.x;
    const int l    = tid & 63;
    const int wave = tid >> 6;
    const int m0 = blockIdx.y * 128, n0 = blockIdx.x * 128;
    const int wr = (wave >> 1) * 64, wc = (wave & 1) * 64;
    const int lr = l & 15;
    const int lk = (l >> 4) * 8;

    f32x4 acc[4][4];
#pragma unroll
    for (int m = 0; m < 4; ++m)
#pragma unroll
        for (int n = 0; n < 4; ++n) acc[m][n] = (f32x4){0.f, 0.f, 0.f, 0.f};

    for (int k0 = 0; k0 < K; k0 += 64) {
#pragma unroll
        for (int p = 0; p < 4; ++p) {
            const int idx = tid + p * 256;
            const int r   = idx >> 3;
            const int ce  = (idx & 7) * 8;
            const uint4 av = *reinterpret_cast<const uint4*>(
                &A[(size_t)(m0 + r) * K + k0 + ce]);
            *reinterpret_cast<uint4*>(&As[r][ce]) = av;
            const uint4 bv = *reinterpret_cast<const uint4*>(
                &B[(size_t)(n0 + r) * K + k0 + ce]);
            *reinterpret_cast<uint4*>(&Bs[r][ce]) = bv;
        }
        __syncthreads();

#pragma unroll
        for (int kk = 0; kk < 64; kk += 32) {
            bfrag af[4], bfr[4];
#pragma unroll
            for (int m = 0; m < 4; ++m)
                af[m] = *reinterpret_cast<const bfrag*>(&As[wr + m * 16 + lr][kk + lk]);
#pragma unroll
            for (int n = 0; n < 4; ++n)
                bfr[n] = *reinterpret_cast<const bfrag*>(&Bs[wc + n * 16 + lr][kk + lk]);
#pragma unroll
            for (int m = 0; m < 4; ++m)
#pragma unroll
                for (int n = 0; n < 4; ++n)
                    acc[m][n] = __builtin_amdgcn_mfma_f32_16x16x32_bf16(
                        af[m], bfr[n], acc[m][n], 0, 0, 0);
        }
        __syncthreads();
    }

#pragma unroll
    for (int m = 0; m < 4; ++m) {
        const int row0 = m0 + wr + m * 16 + (l >> 4) * 4;
#pragma unroll
        for (int n = 0; n < 4; ++n) {
            const int col = n0 + wc + n * 16 + lr;
#pragma unroll
            for (int j = 0; j < 4; ++j) {
                if constexpr (OUT_BF16) {
                    ((__hip_bfloat16*)Cv)[(size_t)(row0 + j) * Nc + col] =
                        __float2bfloat16(acc[m][n][j]);
                } else {
                    ((float*)Cv)[(size_t)(row0 + j) * Nc + col] = acc[m][n][j];
                }
            }
        }
    }
}

// ---------------------------------------------------------------------------
// Vt[bh][d][n] = V[b,n,h,d] from qkvb rows.  64x64 LDS tile transpose.
// ---------------------------------------------------------------------------
__global__ __launch_bounds__(256) void transpose_v(const __hip_bfloat16* __restrict__ qkvb,
                                                   __hip_bfloat16* __restrict__ Vt) {
    const int bh = blockIdx.x >> 4;
    const int nc = blockIdx.x & 15;
    const int b = bh >> 4, h = bh & 15;
    __shared__ unsigned short tile[64][80];
    const int t = threadIdx.x;
    {
        const int r = t >> 2, cc = (t & 3) * 16;
        const size_t src = ((size_t)(b * NSEQ + nc * 64 + r)) * 3072 + 2048 + h * 64 + cc;
        const uint4 v0 = *reinterpret_cast<const uint4*>(&qkvb[src]);
        const uint4 v1 = *reinterpret_cast<const uint4*>(&qkvb[src + 8]);
        *reinterpret_cast<uint4*>(&tile[r][cc])     = v0;
        *reinterpret_cast<uint4*>(&tile[r][cc + 8]) = v1;
    }
    __syncthreads();
    {
        const int d = t >> 2, n2 = (t & 3) * 16;
        unsigned int e[16];
#pragma unroll
        for (int k = 0; k < 16; ++k) e[k] = tile[n2 + k][d];
        uint4 o0, o1;
        o0.x = e[0]  | (e[1]  << 16); o0.y = e[2]  | (e[3]  << 16);
        o0.z = e[4]  | (e[5]  << 16); o0.w = e[6]  | (e[7]  << 16);
        o1.x = e[8]  | (e[9]  << 16); o1.y = e[10] | (e[11] << 16);
        o1.z = e[12] | (e[13] << 16); o1.w = e[14] | (e[15] << 16);
        const size_t dst = ((size_t)(bh * 64 + d)) * 1024 + nc * 64 + n2;
        *reinterpret_cast<uint4*>(&Vt[dst])     = o0;
        *reinterpret_cast<uint4*>(&Vt[dst + 8]) = o1;
    }
}

// ---------------------------------------------------------------------------
// Newton solve for one row, scores register-resident, NQ = #256-col quartiles.
// All 64 lanes end with lam/isw.
// ---------------------------------------------------------------------------
template <int NQ>
__device__ inline void newton_row(const unsigned short* __restrict__ Srow,
                                  int ncols, int lane,
                                  float& lam_out, float& isw_out) {
    constexpr int NC = NQ * 2;               // 128-col chunks (u32 per lane each)
    float sv[NC * 2];
#pragma unroll
    for (int t = 0; t < NC; ++t) {
        const int c = lane * 2 + t * 128;
        const unsigned int u = *reinterpret_cast<const unsigned int*>(&Srow[c]);
        float v0 = bf2f_u(u & 0xffffu);
        float v1 = bf2f_u(u >> 16);
        if (t >= NC - 2) {                   // only last 2 chunks can exceed ncols
            v0 = (c     < ncols) ? v0 : -1e30f;
            v1 = (c + 1 < ncols) ? v1 : -1e30f;
        }
        sv[2 * t] = v0; sv[2 * t + 1] = v1;
    }

    float mx = sv[0];
#pragma unroll
    for (int e = 1; e < 2 * NC; ++e) mx = fmaxf(mx, sv[e]);
#pragma unroll
    for (int off = 32; off; off >>= 1) mx = fmaxf(mx, __shfl_xor(mx, off));
    float lam = mx + 1.0f;

    for (int it = 0; it < NUM_ITER; ++it) {
        float f = 0.f, fp = 0.f;
#pragma unroll
        for (int e = 0; e < 2 * NC; ++e) {
            const float inv = __builtin_amdgcn_rcpf(fmaxf(lam - sv[e], EPS));
            f += inv; fp = fmaf(inv, inv, fp);
        }
#pragma unroll
        for (int off = 32; off; off >>= 1) {
            f  += __shfl_xor(f, off);
            fp += __shfl_xor(fp, off);
        }
        lam += (f - 1.0f) / fp;
    }

    float sw = 0.f;
#pragma unroll
    for (int e = 0; e < 2 * NC; ++e)
        sw += __builtin_amdgcn_rcpf(fmaxf(lam - sv[e], EPS));
#pragma unroll
    for (int off = 32; off; off >>= 1) sw += __shfl_xor(sw, off);

    lam_out = lam;
    isw_out = __builtin_amdgcn_rcpf(sw);
}

// ---------------------------------------------------------------------------
// MFMA Stieltjes attention.  Block = (b,h, 16-row Q-tile), 8 waves, 2048 blks.
// P1: S = (Q.K^T)*SCALE via mfma -> bf16 LDS (qt+1 col-tiles, wave-strided).
// P2: one wave per row (2 serial), causality-aware register Newton.
// P2.5: S -> P in place, only cols < r0+32 (all phase 3 reads).
// P3: 4 waves (dt each), two interleaved mfma chains; waves 4-7 retire.
// ---------------------------------------------------------------------------
__global__ __launch_bounds__(512) void attn_mfma(const __hip_bfloat16* __restrict__ qkvb,
                                                 const __hip_bfloat16* __restrict__ Vt,
                                                 __hip_bfloat16* __restrict__ obf) {
    const int tid  = threadIdx.x;
    const int lane = tid & 63;
    const int wave = tid >> 6;               // 0..7
    const int qt = blockIdx.x & 63;
    const int bh = blockIdx.x >> 6;
    const int b = bh >> 4, h = bh & 15;
    const int r0 = qt * 16;

    __shared__ __align__(16) unsigned short S[16][SPAD];   // scores -> weights
    __shared__ __align__(16) unsigned short Qs[16][72];    // bf16 Q tile
    __shared__ float lamS[16], iswS[16];

    const size_t qbase = (size_t)(b * NSEQ) * 3072;
    const int lr  = lane & 15;
    const int lk8 = (lane >> 4) * 8;

    // ---- stage Q tile (16 x 64 bf16) ----
    if (tid < 128) {
        const int r = tid >> 3, c = (tid & 7) * 8;
        const uint4 v = *reinterpret_cast<const uint4*>(
            &qkvb[qbase + (size_t)(r0 + r) * 3072 + h * 64 + c]);
        *reinterpret_cast<uint4*>(&Qs[r][c]) = v;
    }
    __syncthreads();

    // ---- phase 1: QK^T, col-tiles jt = 0..qt, wave-strided ----
    const __hip_bfloat16* kglob = qkvb + qbase + 1024 + h * 64;
    const int ntask = qt + 1;
    for (int jt = wave; jt < ntask; jt += 8) {
        const int jrow = jt * 16 + lr;
        const bfrag a0 = *reinterpret_cast<const bfrag*>(&Qs[lr][lk8]);
        const bfrag a1 = *reinterpret_cast<const bfrag*>(&Qs[lr][32 + lk8]);
        const bfrag b0 = *reinterpret_cast<const bfrag*>(&kglob[(size_t)jrow * 3072 + lk8]);
        const bfrag b1 = *reinterpret_cast<const bfrag*>(&kglob[(size_t)jrow * 3072 + 32 + lk8]);
        f32x4 c = (f32x4){0.f, 0.f, 0.f, 0.f};
        c = __builtin_amdgcn_mfma_f32_16x16x32_bf16(a0, b0, c, 0, 0, 0);
        c = __builtin_amdgcn_mfma_f32_16x16x32_bf16(a1, b1, c, 0, 0, 0);
#pragma unroll
        for (int j = 0; j < 4; ++j) {
            const int row = (lane >> 4) * 4 + j;
            S[row][jt * 16 + lr] = f2bf_u(c[j] * SCALE);
        }
    }
    __syncthreads();

    // ---- phase 2: Newton, one wave per row (2 rows serial) ----
    for (int rr = 0; rr < 2; ++rr) {
        const int row   = wave * 2 + rr;
        const int ncols = r0 + row + 1;
        const int nq    = (ncols + 255) >> 8;      // 1..4 quartiles
        float lam, isw;
        switch (nq) {
            case 1: newton_row<1>(S[row], ncols, lane, lam, isw); break;
            case 2: newton_row<2>(S[row], ncols, lane, lam, isw); break;
            case 3: newton_row<3>(S[row], ncols, lane, lam, isw); break;
            default: newton_row<4>(S[row], ncols, lane, lam, isw); break;
        }
        if (lane == 0) { lamS[row] = lam; iswS[row] = isw; }
    }
    __syncthreads();

    // ---- phase 2.5: S -> P in place, cols [0, r0+32) only ----
    {
        const int perrow = 2 * qt + 4;             // u32x4 units per row
        const int utot   = 16 * perrow;
        for (int u = tid; u < utot; u += 512) {
            const int row = u & 15;
            const int c0  = (u >> 4) * 8;
            const int iq  = r0 + row;
            const float lam = lamS[row];
            const float isw = iswS[row];
            u32x4 sv = *reinterpret_cast<const u32x4*>(&S[row][c0]);
            unsigned int po[4];
#pragma unroll
            for (int k = 0; k < 4; ++k) {
                const float s0 = bf2f_u(sv[k] & 0xffffu);
                const float s1 = bf2f_u(sv[k] >> 16);
                const float w0 = (c0 + 2 * k     <= iq)
                    ? __builtin_amdgcn_rcpf(fmaxf(lam - s0, EPS)) * isw : 0.f;
                const float w1 = (c0 + 2 * k + 1 <= iq)
                    ? __builtin_amdgcn_rcpf(fmaxf(lam - s1, EPS)) * isw : 0.f;
                po[k] = (unsigned)f2bf_u(w0) | ((unsigned)f2bf_u(w1) << 16);
            }
            *reinterpret_cast<u32x4*>(&S[row][c0]) = (u32x4){po[0], po[1], po[2], po[3]};
        }
    }
    __syncthreads();

    // ---- phase 3: O = P.V, 4 waves (dt each), dual mfma chains ----
    if (wave < 4) {
        const int dt = wave;
        const __hip_bfloat16* vtrow = Vt + ((size_t)(bh * 64 + dt * 16 + lr)) * 1024;

        f32x4 acc0 = (f32x4){0.f, 0.f, 0.f, 0.f};
        f32x4 acc1 = (f32x4){0.f, 0.f, 0.f, 0.f};
        for (int j0 = 0; j0 <= r0; j0 += 64) {
            {
                const bfrag pa = *reinterpret_cast<const bfrag*>(&S[lr][j0 + lk8]);
                const bfrag pb = *reinterpret_cast<const bfrag*>(&vtrow[j0 + lk8]);
                acc0 = __builtin_amdgcn_mfma_f32_16x16x32_bf16(pa, pb, acc0, 0, 0, 0);
            }
            if (j0 + 32 <= r0) {
                const bfrag pa = *reinterpret_cast<const bfrag*>(&S[lr][j0 + 32 + lk8]);
                const bfrag pb = *reinterpret_cast<const bfrag*>(&vtrow[j0 + 32 + lk8]);
                acc1 = __builtin_amdgcn_mfma_f32_16x16x32_bf16(pa, pb, acc1, 0, 0, 0);
            }
        }

#pragma unroll
        for (int j = 0; j < 4; ++j) {
            const int row = (lane >> 4) * 4 + j;
            obf[(size_t)(b * NSEQ + r0 + row) * 1024 + h * 64 + dt * 16 + lr] =
                __float2bfloat16(acc0[j] + acc1[j]);
        }
    }
}

extern "C" void kernel_launch(void* const* d_in, const int* in_sizes, int n_in,
                              void* d_out, int out_size, void* d_ws, size_t ws_size,
                              hipStream_t stream) {
    const float* x    = (const float*)d_in[0];   // [B,N,D]
    const float* Wqkv = (const float*)d_in[1];   // [3D, D]
    const float* Wo   = (const float*)d_in[2];   // [D, D]
    float* out = (float*)d_out;                  // [B,N,D] fp32

    const int M = BATCH * NSEQ;                  // 2048
    char* ws = (char*)d_ws;
    __hip_bfloat16* xbf  = (__hip_bfloat16*)ws; ws += (size_t)M * DMODEL * 2;
    __hip_bfloat16* wqbf = (__hip_bfloat16*)ws; ws += (size_t)3 * DMODEL * DMODEL * 2;
    __hip_bfloat16* wobf = (__hip_bfloat16*)ws; ws += (size_t)DMODEL * DMODEL * 2;
    __hip_bfloat16* qkvb = (__hip_bfloat16*)ws; ws += (size_t)M * 3 * DMODEL * 2;
    __hip_bfloat16* Vt   = (__hip_bfloat16*)ws; ws += (size_t)BATCH * HNUM * DH * NSEQ * 2;
    __hip_bfloat16* obf  = (__hip_bfloat16*)ws; ws += (size_t)M * DMODEL * 2;

    dim3 blk(256);
    cast_f32_bf16<<<2048, blk, 0, stream>>>(x,    xbf,  M * DMODEL);
    cast_f32_bf16<<<2048, blk, 0, stream>>>(Wqkv, wqbf, 3 * DMODEL * DMODEL);
    cast_f32_bf16<<<1024, blk, 0, stream>>>(Wo,   wobf, DMODEL * DMODEL);

    dim3 g1(3 * DMODEL / 128, M / 128);          // (24,16)
    gemm_bt<true><<<g1, blk, 0, stream>>>(xbf, wqbf, qkvb, M, 3 * DMODEL, DMODEL);

    transpose_v<<<512, blk, 0, stream>>>(qkvb, Vt);

    attn_mfma<<<2048, dim3(512), 0, stream>>>(qkvb, Vt, obf);

    dim3 g2(DMODEL / 128, M / 128);              // (8,16)
    gemm_bt<false><<<g2, blk, 0, stream>>>(obf, wobf, out, M, DMODEL, DMODEL);
}

// Round 8
// 125.205 us; speedup vs baseline: 8.5590x; 1.0204x over previous
//
#include <hip/hip_runtime.h>
#include <hip/hip_bf16.h>
#include <math.h>

#define HNUM 16
#define DH 64
#define NSEQ 1024
#define BATCH 2
#define DMODEL 1024
#define SCALE 0.125f
#define EPS 1e-6f
#define NUM_ITER 4
#define SPAD 1128   // u16/row: 2256B -> 141 16B-slots (odd) -> frag reads 2-way max

typedef float f32x4 __attribute__((ext_vector_type(4)));
typedef short bfrag __attribute__((ext_vector_type(8)));     // 8 bf16 = 4 VGPR
typedef unsigned int u32x4 __attribute__((ext_vector_type(4)));

__device__ inline float bf2f_u(unsigned int u) {
    return __builtin_bit_cast(float, u << 16);
}
__device__ inline unsigned short f2bf_u(float f) {
    return __builtin_bit_cast(unsigned short, __float2bfloat16(f));
}

// async global->LDS, 16B per lane.  LDS dest = wave-uniform base + lane*16,
// so the lds pointer must be computed lane-linearly (it is, below).
__device__ inline void gload16(const __hip_bfloat16* g, __hip_bfloat16* l) {
    __builtin_amdgcn_global_load_lds(
        (const __attribute__((address_space(1))) void*)g,
        (__attribute__((address_space(3))) void*)l, 16, 0, 0);
}

// ---------------------------------------------------------------------------
// Fused fp32 -> bf16 cast of the three inputs, float4-vectorized.
// ---------------------------------------------------------------------------
__global__ __launch_bounds__(256) void cast3(const float* __restrict__ s0, __hip_bfloat16* __restrict__ d0, int n0,
                                             const float* __restrict__ s1, __hip_bfloat16* __restrict__ d1, int n1,
                                             const float* __restrict__ s2, __hip_bfloat16* __restrict__ d2, int n2) {
    const int stride = gridDim.x * blockDim.x;
    const int tot = n0 + n1 + n2;           // in float4 units
    for (int i = blockIdx.x * blockDim.x + threadIdx.x; i < tot; i += stride) {
        const float* s; __hip_bfloat16* d; int off;
        if (i < n0)            { s = s0; d = d0; off = i; }
        else if (i < n0 + n1)  { s = s1; d = d1; off = i - n0; }
        else                   { s = s2; d = d2; off = i - n0 - n1; }
        const float4 v = *reinterpret_cast<const float4*>(&s[(size_t)off * 4]);
        ushort4 o;
        o.x = f2bf_u(v.x); o.y = f2bf_u(v.y); o.z = f2bf_u(v.z); o.w = f2bf_u(v.w);
        *reinterpret_cast<ushort4*>(&d[(size_t)off * 4]) = o;
    }
}

// ---------------------------------------------------------------------------
// C[M,Nc] = A[M,K] @ B[Nc,K]^T, bf16 in, fp32 accum.  m97 structure:
// 128x128 tile, BK=64, global_load_lds staging into LINEAR LDS, single
// buffer, 2 barriers/K-step.  4 waves, 4x4 frags of mfma 16x16x32.
// ---------------------------------------------------------------------------
template <bool OUT_BF16>
__global__ __launch_bounds__(256) void gemm_bt(const __hip_bfloat16* __restrict__ A,
                                               const __hip_bfloat16* __restrict__ B,
                                               void* __restrict__ Cv,
                                               int M, int Nc, int K) {
    __shared__ __align__(16) __hip_bfloat16 As[128 * 64];
    __shared__ __align__(16) __hip_bfloat16 Bs[128 * 64];
    const int tid  = threadIdx.x;
    const int l    = tid & 63;
    const int wave = tid >> 6;
    const int m0 = blockIdx.y * 128, n0 = blockIdx.x * 128;
    const int wr = (wave >> 1) * 64, wc = (wave & 1) * 64;
    const int lr = l & 15;
    const int lk = (l >> 4) * 8;

    f32x4 acc[4][4];
#pragma unroll
    for (int m = 0; m < 4; ++m)
#pragma unroll
        for (int n = 0; n < 4; ++n) acc[m][n] = (f32x4){0.f, 0.f, 0.f, 0.f};

    for (int k0 = 0; k0 < K; k0 += 64) {
        // stage 2x 128x64 bf16 tiles: 1024 16B-chunks each, 4/thread
#pragma unroll
        for (int p = 0; p < 4; ++p) {
            const int idx = tid + p * 256;           // lane-linear within wave
            const int r = idx >> 3, ce = (idx & 7) * 8;
            gload16(&A[(size_t)(m0 + r) * K + k0 + ce], &As[idx * 8]);
        }
#pragma unroll
        for (int p = 0; p < 4; ++p) {
            const int idx = tid + p * 256;
            const int r = idx >> 3, ce = (idx & 7) * 8;
            gload16(&B[(size_t)(n0 + r) * K + k0 + ce], &Bs[idx * 8]);
        }
        __syncthreads();                              // drains vmcnt(0) too

#pragma unroll
        for (int kk = 0; kk < 64; kk += 32) {
            bfrag af[4], bfr[4];
#pragma unroll
            for (int m = 0; m < 4; ++m)
                af[m] = *reinterpret_cast<const bfrag*>(&As[(wr + m * 16 + lr) * 64 + kk + lk]);
#pragma unroll
            for (int n = 0; n < 4; ++n)
                bfr[n] = *reinterpret_cast<const bfrag*>(&Bs[(wc + n * 16 + lr) * 64 + kk + lk]);
#pragma unroll
            for (int m = 0; m < 4; ++m)
#pragma unroll
                for (int n = 0; n < 4; ++n)
                    acc[m][n] = __builtin_amdgcn_mfma_f32_16x16x32_bf16(
                        af[m], bfr[n], acc[m][n], 0, 0, 0);
        }
        __syncthreads();
    }

#pragma unroll
    for (int m = 0; m < 4; ++m) {
        const int row0 = m0 + wr + m * 16 + (l >> 4) * 4;
#pragma unroll
        for (int n = 0; n < 4; ++n) {
            const int col = n0 + wc + n * 16 + lr;
#pragma unroll
            for (int j = 0; j < 4; ++j) {
                if constexpr (OUT_BF16) {
                    ((__hip_bfloat16*)Cv)[(size_t)(row0 + j) * Nc + col] =
                        __float2bfloat16(acc[m][n][j]);
                } else {
                    ((float*)Cv)[(size_t)(row0 + j) * Nc + col] = acc[m][n][j];
                }
            }
        }
    }
}

// ---------------------------------------------------------------------------
// Vt[bh][d][n] = V[b,n,h,d] from qkvb rows.  64x64 LDS tile transpose.
// ---------------------------------------------------------------------------
__global__ __launch_bounds__(256) void transpose_v(const __hip_bfloat16* __restrict__ qkvb,
                                                   __hip_bfloat16* __restrict__ Vt) {
    const int bh = blockIdx.x >> 4;
    const int nc = blockIdx.x & 15;
    const int b = bh >> 4, h = bh & 15;
    __shared__ unsigned short tile[64][80];
    const int t = threadIdx.x;
    {
        const int r = t >> 2, cc = (t & 3) * 16;
        const size_t src = ((size_t)(b * NSEQ + nc * 64 + r)) * 3072 + 2048 + h * 64 + cc;
        const uint4 v0 = *reinterpret_cast<const uint4*>(&qkvb[src]);
        const uint4 v1 = *reinterpret_cast<const uint4*>(&qkvb[src + 8]);
        *reinterpret_cast<uint4*>(&tile[r][cc])     = v0;
        *reinterpret_cast<uint4*>(&tile[r][cc + 8]) = v1;
    }
    __syncthreads();
    {
        const int d = t >> 2, n2 = (t & 3) * 16;
        unsigned int e[16];
#pragma unroll
        for (int k = 0; k < 16; ++k) e[k] = tile[n2 + k][d];
        uint4 o0, o1;
        o0.x = e[0]  | (e[1]  << 16); o0.y = e[2]  | (e[3]  << 16);
        o0.z = e[4]  | (e[5]  << 16); o0.w = e[6]  | (e[7]  << 16);
        o1.x = e[8]  | (e[9]  << 16); o1.y = e[10] | (e[11] << 16);
        o1.z = e[12] | (e[13] << 16); o1.w = e[14] | (e[15] << 16);
        const size_t dst = ((size_t)(bh * 64 + d)) * 1024 + nc * 64 + n2;
        *reinterpret_cast<uint4*>(&Vt[dst])     = o0;
        *reinterpret_cast<uint4*>(&Vt[dst + 8]) = o1;
    }
}

// ---------------------------------------------------------------------------
// Newton solve + in-register P write-back for one row.  NQ = 256-col blocks.
// Loads scores once; last pass leaves inv in sv[]; write-back stores the
// normalized bf16 weights for cols < limit (= r0+16, block-uniform).
// Cols in [ncols, limit) get ~1e-30*isw ~ 0 automatically.
// ---------------------------------------------------------------------------
template <int NQ>
__device__ inline void newton_row_wb(unsigned short* __restrict__ Srow,
                                     int ncols, int limit, int lane) {
    constexpr int NC = NQ * 2;               // 128-col chunks
    float sv[NC * 2];
#pragma unroll
    for (int t = 0; t < NC; ++t) {
        const int c = lane * 2 + t * 128;
        const unsigned int u = *reinterpret_cast<const unsigned int*>(&Srow[c]);
        float v0 = bf2f_u(u & 0xffffu);
        float v1 = bf2f_u(u >> 16);
        if (t >= NC - 2) {                   // only last 2 chunks can pass ncols
            v0 = (c     < ncols) ? v0 : -1e30f;
            v1 = (c + 1 < ncols) ? v1 : -1e30f;
        }
        sv[2 * t] = v0; sv[2 * t + 1] = v1;
    }

    float mx = sv[0];
#pragma unroll
    for (int e = 1; e < 2 * NC; ++e) mx = fmaxf(mx, sv[e]);
#pragma unroll
    for (int off = 32; off; off >>= 1) mx = fmaxf(mx, __shfl_xor(mx, off));
    float lam = mx + 1.0f;

    for (int it = 0; it < NUM_ITER; ++it) {
        float f = 0.f, fp = 0.f;
#pragma unroll
        for (int e = 0; e < 2 * NC; ++e) {
            const float inv = __builtin_amdgcn_rcpf(fmaxf(lam - sv[e], EPS));
            f += inv; fp = fmaf(inv, inv, fp);
        }
#pragma unroll
        for (int off = 32; off; off >>= 1) {
            f  += __shfl_xor(f, off);
            fp += __shfl_xor(fp, off);
        }
        lam += (f - 1.0f) / fp;
    }

    // final pass: inv -> sv (reuse), sum -> isw
    float sw = 0.f;
#pragma unroll
    for (int e = 0; e < 2 * NC; ++e) {
        sv[e] = __builtin_amdgcn_rcpf(fmaxf(lam - sv[e], EPS));
        sw += sv[e];
    }
#pragma unroll
    for (int off = 32; off; off >>= 1) sw += __shfl_xor(sw, off);
    const float isw = __builtin_amdgcn_rcpf(sw);

    // write-back normalized bf16 weights, cols < limit only
#pragma unroll
    for (int t = 0; t < NC; ++t) {
        const int c = lane * 2 + t * 128;
        if (t * 128 < limit && c < limit) {
            const unsigned int pk = (unsigned)f2bf_u(sv[2 * t] * isw)
                                  | ((unsigned)f2bf_u(sv[2 * t + 1] * isw) << 16);
            *reinterpret_cast<unsigned int*>(&Srow[c]) = pk;
        }
    }
}

// ---------------------------------------------------------------------------
// MFMA Stieltjes attention.  Block = (b,h, 16-row Q-tile), 8 waves.
// P1: S = (Q.K^T)*SCALE via mfma -> bf16 LDS.
// P2: zero-strip cols [r0+16, r0+112) + per-wave register Newton with fused
//     P write-back (no separate S->P pass, one less barrier).
// P3: O = P.V, 4 waves, dual mfma chains.  All cols P3 reads are defined.
// ---------------------------------------------------------------------------
__global__ __launch_bounds__(512) void attn_mfma(const __hip_bfloat16* __restrict__ qkvb,
                                                 const __hip_bfloat16* __restrict__ Vt,
                                                 __hip_bfloat16* __restrict__ obf) {
    const int tid  = threadIdx.x;
    const int lane = tid & 63;
    const int wave = tid >> 6;               // 0..7
    const int qt = blockIdx.x & 63;
    const int bh = blockIdx.x >> 6;
    const int b = bh >> 4, h = bh & 15;
    const int r0 = qt * 16;

    __shared__ __align__(16) unsigned short S[16][SPAD];   // scores -> weights
    __shared__ __align__(16) unsigned short Qs[16][72];    // bf16 Q tile

    const size_t qbase = (size_t)(b * NSEQ) * 3072;
    const int lr  = lane & 15;
    const int lk8 = (lane >> 4) * 8;

    // ---- stage Q tile (16 x 64 bf16) ----
    if (tid < 128) {
        const int r = tid >> 3, c = (tid & 7) * 8;
        const uint4 v = *reinterpret_cast<const uint4*>(
            &qkvb[qbase + (size_t)(r0 + r) * 3072 + h * 64 + c]);
        *reinterpret_cast<uint4*>(&Qs[r][c]) = v;
    }
    __syncthreads();

    // ---- phase 1: QK^T, col-tiles jt = 0..qt, wave-strided ----
    const __hip_bfloat16* kglob = qkvb + qbase + 1024 + h * 64;
    const int ntask = qt + 1;
    const bfrag a0 = *reinterpret_cast<const bfrag*>(&Qs[lr][lk8]);
    const bfrag a1 = *reinterpret_cast<const bfrag*>(&Qs[lr][32 + lk8]);
    for (int jt = wave; jt < ntask; jt += 8) {
        const int jrow = jt * 16 + lr;
        const bfrag b0 = *reinterpret_cast<const bfrag*>(&kglob[(size_t)jrow * 3072 + lk8]);
        const bfrag b1 = *reinterpret_cast<const bfrag*>(&kglob[(size_t)jrow * 3072 + 32 + lk8]);
        f32x4 c = (f32x4){0.f, 0.f, 0.f, 0.f};
        c = __builtin_amdgcn_mfma_f32_16x16x32_bf16(a0, b0, c, 0, 0, 0);
        c = __builtin_amdgcn_mfma_f32_16x16x32_bf16(a1, b1, c, 0, 0, 0);
#pragma unroll
        for (int j = 0; j < 4; ++j) {
            const int row = (lane >> 4) * 4 + j;
            S[row][jt * 16 + lr] = f2bf_u(c[j] * SCALE);
        }
    }
    __syncthreads();

    // ---- phase 2: zero-strip + Newton w/ fused write-back ----
    if (tid < 192) {                          // 16 rows x 12 u32x4 units
        const int row = tid / 12;
        const int cu  = tid - row * 12;
        *reinterpret_cast<u32x4*>(&S[row][r0 + 16 + cu * 8]) = (u32x4){0u, 0u, 0u, 0u};
    }
    const int limit = r0 + 16;
    for (int rr = 0; rr < 2; ++rr) {
        const int row   = wave * 2 + rr;
        const int ncols = r0 + row + 1;
        const int nq    = (ncols + 255) >> 8;      // 1..4
        switch (nq) {
            case 1:  newton_row_wb<1>(S[row], ncols, limit, lane); break;
            case 2:  newton_row_wb<2>(S[row], ncols, limit, lane); break;
            case 3:  newton_row_wb<3>(S[row], ncols, limit, lane); break;
            default: newton_row_wb<4>(S[row], ncols, limit, lane); break;
        }
    }
    __syncthreads();

    // ---- phase 3: O = P.V, 4 waves (dt each), dual mfma chains ----
    if (wave < 4) {
        const int dt = wave;
        const __hip_bfloat16* vtrow = Vt + ((size_t)(bh * 64 + dt * 16 + lr)) * 1024;

        f32x4 acc0 = (f32x4){0.f, 0.f, 0.f, 0.f};
        f32x4 acc1 = (f32x4){0.f, 0.f, 0.f, 0.f};
        for (int j0 = 0; j0 <= r0; j0 += 64) {
            {
                const bfrag pa = *reinterpret_cast<const bfrag*>(&S[lr][j0 + lk8]);
                const bfrag pb = *reinterpret_cast<const bfrag*>(&vtrow[j0 + lk8]);
                acc0 = __builtin_amdgcn_mfma_f32_16x16x32_bf16(pa, pb, acc0, 0, 0, 0);
            }
            if (j0 + 32 <= r0) {
                const bfrag pa = *reinterpret_cast<const bfrag*>(&S[lr][j0 + 32 + lk8]);
                const bfrag pb = *reinterpret_cast<const bfrag*>(&vtrow[j0 + 32 + lk8]);
                acc1 = __builtin_amdgcn_mfma_f32_16x16x32_bf16(pa, pb, acc1, 0, 0, 0);
            }
        }

#pragma unroll
        for (int j = 0; j < 4; ++j) {
            const int row = (lane >> 4) * 4 + j;
            obf[(size_t)(b * NSEQ + r0 + row) * 1024 + h * 64 + dt * 16 + lr] =
                __float2bfloat16(acc0[j] + acc1[j]);
        }
    }
}

extern "C" void kernel_launch(void* const* d_in, const int* in_sizes, int n_in,
                              void* d_out, int out_size, void* d_ws, size_t ws_size,
                              hipStream_t stream) {
    const float* x    = (const float*)d_in[0];   // [B,N,D]
    const float* Wqkv = (const float*)d_in[1];   // [3D, D]
    const float* Wo   = (const float*)d_in[2];   // [D, D]
    float* out = (float*)d_out;                  // [B,N,D] fp32

    const int M = BATCH * NSEQ;                  // 2048
    char* ws = (char*)d_ws;
    __hip_bfloat16* xbf  = (__hip_bfloat16*)ws; ws += (size_t)M * DMODEL * 2;
    __hip_bfloat16* wqbf = (__hip_bfloat16*)ws; ws += (size_t)3 * DMODEL * DMODEL * 2;
    __hip_bfloat16* wobf = (__hip_bfloat16*)ws; ws += (size_t)DMODEL * DMODEL * 2;
    __hip_bfloat16* qkvb = (__hip_bfloat16*)ws; ws += (size_t)M * 3 * DMODEL * 2;
    __hip_bfloat16* Vt   = (__hip_bfloat16*)ws; ws += (size_t)BATCH * HNUM * DH * NSEQ * 2;
    __hip_bfloat16* obf  = (__hip_bfloat16*)ws; ws += (size_t)M * DMODEL * 2;

    dim3 blk(256);
    cast3<<<2048, blk, 0, stream>>>(x, xbf, M * DMODEL / 4,
                                    Wqkv, wqbf, 3 * DMODEL * DMODEL / 4,
                                    Wo, wobf, DMODEL * DMODEL / 4);

    dim3 g1(3 * DMODEL / 128, M / 128);          // (24,16)
    gemm_bt<true><<<g1, blk, 0, stream>>>(xbf, wqbf, qkvb, M, 3 * DMODEL, DMODEL);

    transpose_v<<<512, blk, 0, stream>>>(qkvb, Vt);

    attn_mfma<<<2048, dim3(512), 0, stream>>>(qkvb, Vt, obf);

    dim3 g2(DMODEL / 128, M / 128);              // (8,16)
    gemm_bt<false><<<g2, blk, 0, stream>>>(obf, wobf, out, M, DMODEL, DMODEL);
}

// Round 9
// 122.053 us; speedup vs baseline: 8.7800x; 1.0258x over previous
//
#include <hip/hip_runtime.h>
#include <hip/hip_bf16.h>
#include <math.h>

#define HNUM 16
#define DH 64
#define NSEQ 1024
#define BATCH 2
#define DMODEL 1024
#define SCALE 0.125f
#define EPS 1e-6f
#define NUM_ITER 4
#define SPAD 1048   // u16/row: 2096B = 131 16B-slots (odd) -> frag reads 2-way max (free)

typedef float f32x4 __attribute__((ext_vector_type(4)));
typedef short bfrag __attribute__((ext_vector_type(8)));     // 8 bf16 = 4 VGPR
typedef unsigned int u32x4 __attribute__((ext_vector_type(4)));

__device__ inline float bf2f_u(unsigned int u) {
    return __builtin_bit_cast(float, u << 16);
}
__device__ inline unsigned short f2bf_u(float f) {
    return __builtin_bit_cast(unsigned short, __float2bfloat16(f));
}

// async global->LDS, 16B per lane; LDS dest must be lane-linear (it is).
__device__ inline void gload16(const __hip_bfloat16* g, __hip_bfloat16* l) {
    __builtin_amdgcn_global_load_lds(
        (const __attribute__((address_space(1))) void*)g,
        (__attribute__((address_space(3))) void*)l, 16, 0, 0);
}

// ---------------------------------------------------------------------------
// Fused fp32 -> bf16 cast of the three inputs, float4-vectorized.
// ---------------------------------------------------------------------------
__global__ __launch_bounds__(256) void cast3(const float* __restrict__ s0, __hip_bfloat16* __restrict__ d0, int n0,
                                             const float* __restrict__ s1, __hip_bfloat16* __restrict__ d1, int n1,
                                             const float* __restrict__ s2, __hip_bfloat16* __restrict__ d2, int n2) {
    const int stride = gridDim.x * blockDim.x;
    const int tot = n0 + n1 + n2;           // in float4 units
    for (int i = blockIdx.x * blockDim.x + threadIdx.x; i < tot; i += stride) {
        const float* s; __hip_bfloat16* d; int off;
        if (i < n0)            { s = s0; d = d0; off = i; }
        else if (i < n0 + n1)  { s = s1; d = d1; off = i - n0; }
        else                   { s = s2; d = d2; off = i - n0 - n1; }
        const float4 v = *reinterpret_cast<const float4*>(&s[(size_t)off * 4]);
        ushort4 o;
        o.x = f2bf_u(v.x); o.y = f2bf_u(v.y); o.z = f2bf_u(v.z); o.w = f2bf_u(v.w);
        *reinterpret_cast<ushort4*>(&d[(size_t)off * 4]) = o;
    }
}

// ---------------------------------------------------------------------------
// C[M,Nc] = A[M,K] @ B[Nc,K]^T, bf16 in, fp32 accum.  64x128 tile, BK=64,
// global_load_lds staging, linear LDS, 4 waves each 32x64 (2x4 frags).
// More blocks than 128x128 -> even CU balance for our small shapes.
// ---------------------------------------------------------------------------
template <bool OUT_BF16>
__global__ __launch_bounds__(256) void gemm_bt(const __hip_bfloat16* __restrict__ A,
                                               const __hip_bfloat16* __restrict__ B,
                                               void* __restrict__ Cv,
                                               int M, int Nc, int K) {
    __shared__ __align__(16) __hip_bfloat16 As[64 * 64];
    __shared__ __align__(16) __hip_bfloat16 Bs[128 * 64];
    const int tid  = threadIdx.x;
    const int l    = tid & 63;
    const int wave = tid >> 6;
    const int m0 = blockIdx.y * 64, n0 = blockIdx.x * 128;
    const int wr = (wave >> 1) * 32, wc = (wave & 1) * 64;
    const int lr = l & 15;
    const int lk = (l >> 4) * 8;

    f32x4 acc[2][4];
#pragma unroll
    for (int m = 0; m < 2; ++m)
#pragma unroll
        for (int n = 0; n < 4; ++n) acc[m][n] = (f32x4){0.f, 0.f, 0.f, 0.f};

    for (int k0 = 0; k0 < K; k0 += 64) {
        // A: 64x64 = 512 16B-chunks, 2/thread; B: 128x64 = 1024 chunks, 4/thread
#pragma unroll
        for (int p = 0; p < 2; ++p) {
            const int idx = tid + p * 256;
            const int r = idx >> 3, ce = (idx & 7) * 8;
            gload16(&A[(size_t)(m0 + r) * K + k0 + ce], &As[idx * 8]);
        }
#pragma unroll
        for (int p = 0; p < 4; ++p) {
            const int idx = tid + p * 256;
            const int r = idx >> 3, ce = (idx & 7) * 8;
            gload16(&B[(size_t)(n0 + r) * K + k0 + ce], &Bs[idx * 8]);
        }
        __syncthreads();                              // drains vmcnt too

#pragma unroll
        for (int kk = 0; kk < 64; kk += 32) {
            bfrag af[2], bfr[4];
#pragma unroll
            for (int m = 0; m < 2; ++m)
                af[m] = *reinterpret_cast<const bfrag*>(&As[(wr + m * 16 + lr) * 64 + kk + lk]);
#pragma unroll
            for (int n = 0; n < 4; ++n)
                bfr[n] = *reinterpret_cast<const bfrag*>(&Bs[(wc + n * 16 + lr) * 64 + kk + lk]);
#pragma unroll
            for (int m = 0; m < 2; ++m)
#pragma unroll
                for (int n = 0; n < 4; ++n)
                    acc[m][n] = __builtin_amdgcn_mfma_f32_16x16x32_bf16(
                        af[m], bfr[n], acc[m][n], 0, 0, 0);
        }
        __syncthreads();
    }

#pragma unroll
    for (int m = 0; m < 2; ++m) {
        const int row0 = m0 + wr + m * 16 + (l >> 4) * 4;
#pragma unroll
        for (int n = 0; n < 4; ++n) {
            const int col = n0 + wc + n * 16 + lr;
#pragma unroll
            for (int j = 0; j < 4; ++j) {
                if constexpr (OUT_BF16) {
                    ((__hip_bfloat16*)Cv)[(size_t)(row0 + j) * Nc + col] =
                        __float2bfloat16(acc[m][n][j]);
                } else {
                    ((float*)Cv)[(size_t)(row0 + j) * Nc + col] = acc[m][n][j];
                }
            }
        }
    }
}

// ---------------------------------------------------------------------------
// Vt[bh][d][n] = V[b,n,h,d] from qkvb rows.  64x64 LDS tile transpose.
// ---------------------------------------------------------------------------
__global__ __launch_bounds__(256) void transpose_v(const __hip_bfloat16* __restrict__ qkvb,
                                                   __hip_bfloat16* __restrict__ Vt) {
    const int bh = blockIdx.x >> 4;
    const int nc = blockIdx.x & 15;
    const int b = bh >> 4, h = bh & 15;
    __shared__ unsigned short tile[64][80];
    const int t = threadIdx.x;
    {
        const int r = t >> 2, cc = (t & 3) * 16;
        const size_t src = ((size_t)(b * NSEQ + nc * 64 + r)) * 3072 + 2048 + h * 64 + cc;
        const uint4 v0 = *reinterpret_cast<const uint4*>(&qkvb[src]);
        const uint4 v1 = *reinterpret_cast<const uint4*>(&qkvb[src + 8]);
        *reinterpret_cast<uint4*>(&tile[r][cc])     = v0;
        *reinterpret_cast<uint4*>(&tile[r][cc + 8]) = v1;
    }
    __syncthreads();
    {
        const int d = t >> 2, n2 = (t & 3) * 16;
        unsigned int e[16];
#pragma unroll
        for (int k = 0; k < 16; ++k) e[k] = tile[n2 + k][d];
        uint4 o0, o1;
        o0.x = e[0]  | (e[1]  << 16); o0.y = e[2]  | (e[3]  << 16);
        o0.z = e[4]  | (e[5]  << 16); o0.w = e[6]  | (e[7]  << 16);
        o1.x = e[8]  | (e[9]  << 16); o1.y = e[10] | (e[11] << 16);
        o1.z = e[12] | (e[13] << 16); o1.w = e[14] | (e[15] << 16);
        const size_t dst = ((size_t)(bh * 64 + d)) * 1024 + nc * 64 + n2;
        *reinterpret_cast<uint4*>(&Vt[dst])     = o0;
        *reinterpret_cast<uint4*>(&Vt[dst + 8]) = o1;
    }
}

// ---------------------------------------------------------------------------
// Dual-row Newton + fused P write-back.  Rows A,B processed INTERLEAVED so
// the shuffle-reduce chains overlap (2x ILP on the latency-critical path).
// NQ sized for row B (the larger); row A = B-1 cols, masks still confined to
// the last two 128-col chunks.  Write-back: cols < limit get normalized bf16
// weights (invalid cols ~1e-30*isw ~ 0).
// ---------------------------------------------------------------------------
template <int NQ>
__device__ inline void newton2_wb(unsigned short* __restrict__ SA,
                                  unsigned short* __restrict__ SB,
                                  int ncolsA, int ncolsB, int limit, int lane) {
    constexpr int NC = NQ * 2;               // 128-col chunks
    float svA[NC * 2], svB[NC * 2];
#pragma unroll
    for (int t = 0; t < NC; ++t) {
        const int c = lane * 2 + t * 128;
        const unsigned int uA = *reinterpret_cast<const unsigned int*>(&SA[c]);
        const unsigned int uB = *reinterpret_cast<const unsigned int*>(&SB[c]);
        float a0 = bf2f_u(uA & 0xffffu), a1 = bf2f_u(uA >> 16);
        float b0 = bf2f_u(uB & 0xffffu), b1 = bf2f_u(uB >> 16);
        if (t >= NC - 2) {
            a0 = (c     < ncolsA) ? a0 : -1e30f;
            a1 = (c + 1 < ncolsA) ? a1 : -1e30f;
            b0 = (c     < ncolsB) ? b0 : -1e30f;
            b1 = (c + 1 < ncolsB) ? b1 : -1e30f;
        }
        svA[2 * t] = a0; svA[2 * t + 1] = a1;
        svB[2 * t] = b0; svB[2 * t + 1] = b1;
    }

    float mA = svA[0], mB = svB[0];
#pragma unroll
    for (int e = 1; e < 2 * NC; ++e) { mA = fmaxf(mA, svA[e]); mB = fmaxf(mB, svB[e]); }
#pragma unroll
    for (int off = 32; off; off >>= 1) {
        mA = fmaxf(mA, __shfl_xor(mA, off));
        mB = fmaxf(mB, __shfl_xor(mB, off));
    }
    float lamA = mA + 1.0f, lamB = mB + 1.0f;

    for (int it = 0; it < NUM_ITER; ++it) {
        float fA = 0.f, fpA = 0.f, fB = 0.f, fpB = 0.f;
#pragma unroll
        for (int e = 0; e < 2 * NC; ++e) {
            const float iA = __builtin_amdgcn_rcpf(fmaxf(lamA - svA[e], EPS));
            fA += iA; fpA = fmaf(iA, iA, fpA);
            const float iB = __builtin_amdgcn_rcpf(fmaxf(lamB - svB[e], EPS));
            fB += iB; fpB = fmaf(iB, iB, fpB);
        }
#pragma unroll
        for (int off = 32; off; off >>= 1) {
            fA += __shfl_xor(fA, off); fpA += __shfl_xor(fpA, off);
            fB += __shfl_xor(fB, off); fpB += __shfl_xor(fpB, off);
        }
        lamA += (fA - 1.0f) / fpA;
        lamB += (fB - 1.0f) / fpB;
    }

    // final pass: inv -> sv (reuse), sums -> isw
    float swA = 0.f, swB = 0.f;
#pragma unroll
    for (int e = 0; e < 2 * NC; ++e) {
        svA[e] = __builtin_amdgcn_rcpf(fmaxf(lamA - svA[e], EPS)); swA += svA[e];
        svB[e] = __builtin_amdgcn_rcpf(fmaxf(lamB - svB[e], EPS)); swB += svB[e];
    }
#pragma unroll
    for (int off = 32; off; off >>= 1) {
        swA += __shfl_xor(swA, off);
        swB += __shfl_xor(swB, off);
    }
    const float iswA = __builtin_amdgcn_rcpf(swA);
    const float iswB = __builtin_amdgcn_rcpf(swB);

#pragma unroll
    for (int t = 0; t < NC; ++t) {
        const int c = lane * 2 + t * 128;
        if (t * 128 < limit && c < limit) {
            const unsigned int pA = (unsigned)f2bf_u(svA[2 * t] * iswA)
                                  | ((unsigned)f2bf_u(svA[2 * t + 1] * iswA) << 16);
            *reinterpret_cast<unsigned int*>(&SA[c]) = pA;
            const unsigned int pB = (unsigned)f2bf_u(svB[2 * t] * iswB)
                                  | ((unsigned)f2bf_u(svB[2 * t + 1] * iswB) << 16);
            *reinterpret_cast<unsigned int*>(&SB[c]) = pB;
        }
    }
}

// ---------------------------------------------------------------------------
// MFMA Stieltjes attention.  Block = (b,h, 16-row Q-tile), 8 waves.
// P1: QK^T via mfma (Q frags straight from global -- no Q LDS, no barrier);
//     task jt==qt+1 zeroes the 16-col strip [r0+16, r0+32) that P3 overreads.
// P2: dual-row register Newton with fused P write-back.
// P3: O = P.V, 4 waves, dual mfma chains (reads only cols < r0+32, defined).
// ---------------------------------------------------------------------------
__global__ __launch_bounds__(512) void attn_mfma(const __hip_bfloat16* __restrict__ qkvb,
                                                 const __hip_bfloat16* __restrict__ Vt,
                                                 __hip_bfloat16* __restrict__ obf) {
    const int tid  = threadIdx.x;
    const int lane = tid & 63;
    const int wave = tid >> 6;               // 0..7
    const int qt = blockIdx.x & 63;
    const int bh = blockIdx.x >> 6;
    const int b = bh >> 4, h = bh & 15;
    const int r0 = qt * 16;

    __shared__ __align__(16) unsigned short S[16][SPAD];   // scores -> weights

    const size_t qbase = (size_t)(b * NSEQ) * 3072;
    const int lr  = lane & 15;
    const int lk8 = (lane >> 4) * 8;
    const int rj0 = (lane >> 4) * 4;

    // ---- phase 1: QK^T, col-tiles jt = 0..qt (+ zero strip at qt+1) ----
    const __hip_bfloat16* qrow = qkvb + qbase + (size_t)(r0 + lr) * 3072 + h * 64;
    const bfrag a0 = *reinterpret_cast<const bfrag*>(&qrow[lk8]);
    const bfrag a1 = *reinterpret_cast<const bfrag*>(&qrow[32 + lk8]);
    const __hip_bfloat16* kglob = qkvb + qbase + 1024 + h * 64;
    for (int jt = wave; jt <= qt + 1; jt += 8) {
        if (jt <= qt) {
            const int jrow = jt * 16 + lr;
            const bfrag b0 = *reinterpret_cast<const bfrag*>(&kglob[(size_t)jrow * 3072 + lk8]);
            const bfrag b1 = *reinterpret_cast<const bfrag*>(&kglob[(size_t)jrow * 3072 + 32 + lk8]);
            f32x4 c = (f32x4){0.f, 0.f, 0.f, 0.f};
            c = __builtin_amdgcn_mfma_f32_16x16x32_bf16(a0, b0, c, 0, 0, 0);
            c = __builtin_amdgcn_mfma_f32_16x16x32_bf16(a1, b1, c, 0, 0, 0);
#pragma unroll
            for (int j = 0; j < 4; ++j)
                S[rj0 + j][jt * 16 + lr] = f2bf_u(c[j] * SCALE);
        } else {
#pragma unroll
            for (int j = 0; j < 4; ++j)
                S[rj0 + j][jt * 16 + lr] = 0;
        }
    }
    __syncthreads();

    // ---- phase 2: dual-row Newton w/ fused write-back ----
    {
        const int rowA = wave * 2, rowB = rowA + 1;
        const int ncolsA = r0 + rowA + 1, ncolsB = r0 + rowB + 1;
        const int limit = r0 + 16;
        const int nq = (ncolsB + 255) >> 8;        // 1..4 (row B is larger)
        switch (nq) {
            case 1:  newton2_wb<1>(S[rowA], S[rowB], ncolsA, ncolsB, limit, lane); break;
            case 2:  newton2_wb<2>(S[rowA], S[rowB], ncolsA, ncolsB, limit, lane); break;
            case 3:  newton2_wb<3>(S[rowA], S[rowB], ncolsA, ncolsB, limit, lane); break;
            default: newton2_wb<4>(S[rowA], S[rowB], ncolsA, ncolsB, limit, lane); break;
        }
    }
    __syncthreads();

    // ---- phase 3: O = P.V, 4 waves (dt each), dual mfma chains ----
    if (wave < 4) {
        const int dt = wave;
        const __hip_bfloat16* vtrow = Vt + ((size_t)(bh * 64 + dt * 16 + lr)) * 1024;

        f32x4 acc0 = (f32x4){0.f, 0.f, 0.f, 0.f};
        f32x4 acc1 = (f32x4){0.f, 0.f, 0.f, 0.f};
        for (int j0 = 0; j0 <= r0; j0 += 64) {
            {
                const bfrag pa = *reinterpret_cast<const bfrag*>(&S[lr][j0 + lk8]);
                const bfrag pb = *reinterpret_cast<const bfrag*>(&vtrow[j0 + lk8]);
                acc0 = __builtin_amdgcn_mfma_f32_16x16x32_bf16(pa, pb, acc0, 0, 0, 0);
            }
            if (j0 + 32 <= r0) {
                const bfrag pa = *reinterpret_cast<const bfrag*>(&S[lr][j0 + 32 + lk8]);
                const bfrag pb = *reinterpret_cast<const bfrag*>(&vtrow[j0 + 32 + lk8]);
                acc1 = __builtin_amdgcn_mfma_f32_16x16x32_bf16(pa, pb, acc1, 0, 0, 0);
            }
        }

#pragma unroll
        for (int j = 0; j < 4; ++j) {
            const int row = rj0 + j;
            obf[(size_t)(b * NSEQ + r0 + row) * 1024 + h * 64 + dt * 16 + lr] =
                __float2bfloat16(acc0[j] + acc1[j]);
        }
    }
}

extern "C" void kernel_launch(void* const* d_in, const int* in_sizes, int n_in,
                              void* d_out, int out_size, void* d_ws, size_t ws_size,
                              hipStream_t stream) {
    const float* x    = (const float*)d_in[0];   // [B,N,D]
    const float* Wqkv = (const float*)d_in[1];   // [3D, D]
    const float* Wo   = (const float*)d_in[2];   // [D, D]
    float* out = (float*)d_out;                  // [B,N,D] fp32

    const int M = BATCH * NSEQ;                  // 2048
    char* ws = (char*)d_ws;
    __hip_bfloat16* xbf  = (__hip_bfloat16*)ws; ws += (size_t)M * DMODEL * 2;
    __hip_bfloat16* wqbf = (__hip_bfloat16*)ws; ws += (size_t)3 * DMODEL * DMODEL * 2;
    __hip_bfloat16* wobf = (__hip_bfloat16*)ws; ws += (size_t)DMODEL * DMODEL * 2;
    __hip_bfloat16* qkvb = (__hip_bfloat16*)ws; ws += (size_t)M * 3 * DMODEL * 2;
    __hip_bfloat16* Vt   = (__hip_bfloat16*)ws; ws += (size_t)BATCH * HNUM * DH * NSEQ * 2;
    __hip_bfloat16* obf  = (__hip_bfloat16*)ws; ws += (size_t)M * DMODEL * 2;

    dim3 blk(256);
    cast3<<<2048, blk, 0, stream>>>(x, xbf, M * DMODEL / 4,
                                    Wqkv, wqbf, 3 * DMODEL * DMODEL / 4,
                                    Wo, wobf, DMODEL * DMODEL / 4);

    dim3 g1(3 * DMODEL / 128, M / 64);           // (24,32) = 768 blocks
    gemm_bt<true><<<g1, blk, 0, stream>>>(xbf, wqbf, qkvb, M, 3 * DMODEL, DMODEL);

    transpose_v<<<512, blk, 0, stream>>>(qkvb, Vt);

    attn_mfma<<<2048, dim3(512), 0, stream>>>(qkvb, Vt, obf);

    dim3 g2(DMODEL / 128, M / 64);               // (8,32) = 256 blocks
    gemm_bt<false><<<g2, blk, 0, stream>>>(obf, wobf, out, M, DMODEL, DMODEL);
}

// Round 10
// 115.395 us; speedup vs baseline: 9.2866x; 1.0577x over previous
//
#include <hip/hip_runtime.h>
#include <hip/hip_bf16.h>
#include <math.h>

#define HNUM 16
#define DH 64
#define NSEQ 1024
#define BATCH 2
#define DMODEL 1024
#define SCALE 0.125f
#define EPS 1e-6f
#define NUM_ITER 4
#define SPAD_T 1080  // u16/row: 2160B = 135 16B-slots (odd) -> frag reads 2-way max (free)

typedef float f32x4 __attribute__((ext_vector_type(4)));
typedef short bfrag __attribute__((ext_vector_type(8)));     // 8 bf16 = 4 VGPR
typedef unsigned int u32x4 __attribute__((ext_vector_type(4)));

__device__ inline float bf2f_u(unsigned int u) {
    return __builtin_bit_cast(float, u << 16);
}
__device__ inline unsigned short f2bf_u(float f) {
    return __builtin_bit_cast(unsigned short, __float2bfloat16(f));
}

// async global->LDS, 16B per lane; LDS dest must be lane-linear (it is).
__device__ inline void gload16(const __hip_bfloat16* g, __hip_bfloat16* l) {
    __builtin_amdgcn_global_load_lds(
        (const __attribute__((address_space(1))) void*)g,
        (__attribute__((address_space(3))) void*)l, 16, 0, 0);
}

// ---------------------------------------------------------------------------
// Fused fp32 -> bf16 cast of the three inputs, float4-vectorized.
// ---------------------------------------------------------------------------
__global__ __launch_bounds__(256) void cast3(const float* __restrict__ s0, __hip_bfloat16* __restrict__ d0, int n0,
                                             const float* __restrict__ s1, __hip_bfloat16* __restrict__ d1, int n1,
                                             const float* __restrict__ s2, __hip_bfloat16* __restrict__ d2, int n2) {
    const int stride = gridDim.x * blockDim.x;
    const int tot = n0 + n1 + n2;           // in float4 units
    for (int i = blockIdx.x * blockDim.x + threadIdx.x; i < tot; i += stride) {
        const float* s; __hip_bfloat16* d; int off;
        if (i < n0)            { s = s0; d = d0; off = i; }
        else if (i < n0 + n1)  { s = s1; d = d1; off = i - n0; }
        else                   { s = s2; d = d2; off = i - n0 - n1; }
        const float4 v = *reinterpret_cast<const float4*>(&s[(size_t)off * 4]);
        ushort4 o;
        o.x = f2bf_u(v.x); o.y = f2bf_u(v.y); o.z = f2bf_u(v.z); o.w = f2bf_u(v.w);
        *reinterpret_cast<ushort4*>(&d[(size_t)off * 4]) = o;
    }
}

// ---------------------------------------------------------------------------
// C[M,Nc] = A[M,K] @ B[Nc,K]^T, bf16 in, fp32 accum.  64x128 tile, BK=64,
// global_load_lds staging, linear LDS, 4 waves each 32x64 (2x4 frags).
// ---------------------------------------------------------------------------
template <bool OUT_BF16>
__global__ __launch_bounds__(256) void gemm_bt(const __hip_bfloat16* __restrict__ A,
                                               const __hip_bfloat16* __restrict__ B,
                                               void* __restrict__ Cv,
                                               int M, int Nc, int K) {
    __shared__ __align__(16) __hip_bfloat16 As[64 * 64];
    __shared__ __align__(16) __hip_bfloat16 Bs[128 * 64];
    const int tid  = threadIdx.x;
    const int l    = tid & 63;
    const int wave = tid >> 6;
    const int m0 = blockIdx.y * 64, n0 = blockIdx.x * 128;
    const int wr = (wave >> 1) * 32, wc = (wave & 1) * 64;
    const int lr = l & 15;
    const int lk = (l >> 4) * 8;

    f32x4 acc[2][4];
#pragma unroll
    for (int m = 0; m < 2; ++m)
#pragma unroll
        for (int n = 0; n < 4; ++n) acc[m][n] = (f32x4){0.f, 0.f, 0.f, 0.f};

    for (int k0 = 0; k0 < K; k0 += 64) {
#pragma unroll
        for (int p = 0; p < 2; ++p) {
            const int idx = tid + p * 256;
            const int r = idx >> 3, ce = (idx & 7) * 8;
            gload16(&A[(size_t)(m0 + r) * K + k0 + ce], &As[idx * 8]);
        }
#pragma unroll
        for (int p = 0; p < 4; ++p) {
            const int idx = tid + p * 256;
            const int r = idx >> 3, ce = (idx & 7) * 8;
            gload16(&B[(size_t)(n0 + r) * K + k0 + ce], &Bs[idx * 8]);
        }
        __syncthreads();

#pragma unroll
        for (int kk = 0; kk < 64; kk += 32) {
            bfrag af[2], bfr[4];
#pragma unroll
            for (int m = 0; m < 2; ++m)
                af[m] = *reinterpret_cast<const bfrag*>(&As[(wr + m * 16 + lr) * 64 + kk + lk]);
#pragma unroll
            for (int n = 0; n < 4; ++n)
                bfr[n] = *reinterpret_cast<const bfrag*>(&Bs[(wc + n * 16 + lr) * 64 + kk + lk]);
#pragma unroll
            for (int m = 0; m < 2; ++m)
#pragma unroll
                for (int n = 0; n < 4; ++n)
                    acc[m][n] = __builtin_amdgcn_mfma_f32_16x16x32_bf16(
                        af[m], bfr[n], acc[m][n], 0, 0, 0);
        }
        __syncthreads();
    }

#pragma unroll
    for (int m = 0; m < 2; ++m) {
        const int row0 = m0 + wr + m * 16 + (l >> 4) * 4;
#pragma unroll
        for (int n = 0; n < 4; ++n) {
            const int col = n0 + wc + n * 16 + lr;
#pragma unroll
            for (int j = 0; j < 4; ++j) {
                if constexpr (OUT_BF16) {
                    ((__hip_bfloat16*)Cv)[(size_t)(row0 + j) * Nc + col] =
                        __float2bfloat16(acc[m][n][j]);
                } else {
                    ((float*)Cv)[(size_t)(row0 + j) * Nc + col] = acc[m][n][j];
                }
            }
        }
    }
}

// ---------------------------------------------------------------------------
// Vt[bh][d][n] = V[b,n,h,d] from qkvb rows.  64x64 LDS tile transpose.
// ---------------------------------------------------------------------------
__global__ __launch_bounds__(256) void transpose_v(const __hip_bfloat16* __restrict__ qkvb,
                                                   __hip_bfloat16* __restrict__ Vt) {
    const int bh = blockIdx.x >> 4;
    const int nc = blockIdx.x & 15;
    const int b = bh >> 4, h = bh & 15;
    __shared__ unsigned short tile[64][80];
    const int t = threadIdx.x;
    {
        const int r = t >> 2, cc = (t & 3) * 16;
        const size_t src = ((size_t)(b * NSEQ + nc * 64 + r)) * 3072 + 2048 + h * 64 + cc;
        const uint4 v0 = *reinterpret_cast<const uint4*>(&qkvb[src]);
        const uint4 v1 = *reinterpret_cast<const uint4*>(&qkvb[src + 8]);
        *reinterpret_cast<uint4*>(&tile[r][cc])     = v0;
        *reinterpret_cast<uint4*>(&tile[r][cc + 8]) = v1;
    }
    __syncthreads();
    {
        const int d = t >> 2, n2 = (t & 3) * 16;
        unsigned int e[16];
#pragma unroll
        for (int k = 0; k < 16; ++k) e[k] = tile[n2 + k][d];
        uint4 o0, o1;
        o0.x = e[0]  | (e[1]  << 16); o0.y = e[2]  | (e[3]  << 16);
        o0.z = e[4]  | (e[5]  << 16); o0.w = e[6]  | (e[7]  << 16);
        o1.x = e[8]  | (e[9]  << 16); o1.y = e[10] | (e[11] << 16);
        o1.z = e[12] | (e[13] << 16); o1.w = e[14] | (e[15] << 16);
        const size_t dst = ((size_t)(bh * 64 + d)) * 1024 + nc * 64 + n2;
        *reinterpret_cast<uint4*>(&Vt[dst])     = o0;
        *reinterpret_cast<uint4*>(&Vt[dst + 8]) = o1;
    }
}

// ---------------------------------------------------------------------------
// Dual-row Newton + fused P write-back: one A-tile row + one B-tile row
// interleaved (independent chains -> 2x ILP on shuffle reduces; near-constant
// combined length ncolsA+ncolsB).  Masked chunks clamp the LDS address to 0
// (region is only ncols+~32 wide) and overwrite the value with -1e30.
// ---------------------------------------------------------------------------
template <int NQA, int NQB>
__device__ inline void newton2_wb(unsigned short* __restrict__ SA,
                                  unsigned short* __restrict__ SB,
                                  int ncolsA, int ncolsB,
                                  int limitA, int limitB, int lane) {
    constexpr int NCA = NQA * 2, NCB = NQB * 2;    // 128-col chunks
    float svA[NCA * 2], svB[NCB * 2];
#pragma unroll
    for (int t = 0; t < NCA; ++t) {
        const int c = lane * 2 + t * 128;
        int ca = c;
        if (t >= NCA - 2) ca = (c < ncolsA) ? c : 0;       // in-region addr
        const unsigned int u = *reinterpret_cast<const unsigned int*>(&SA[ca]);
        float v0 = bf2f_u(u & 0xffffu), v1 = bf2f_u(u >> 16);
        if (t >= NCA - 2) {
            v0 = (c     < ncolsA) ? v0 : -1e30f;
            v1 = (c + 1 < ncolsA) ? v1 : -1e30f;
        }
        svA[2 * t] = v0; svA[2 * t + 1] = v1;
    }
#pragma unroll
    for (int t = 0; t < NCB; ++t) {
        const int c = lane * 2 + t * 128;
        int cbm = c;
        if (t >= NCB - 2) cbm = (c < ncolsB) ? c : 0;
        const unsigned int u = *reinterpret_cast<const unsigned int*>(&SB[cbm]);
        float v0 = bf2f_u(u & 0xffffu), v1 = bf2f_u(u >> 16);
        if (t >= NCB - 2) {
            v0 = (c     < ncolsB) ? v0 : -1e30f;
            v1 = (c + 1 < ncolsB) ? v1 : -1e30f;
        }
        svB[2 * t] = v0; svB[2 * t + 1] = v1;
    }

    float mA = svA[0], mB = svB[0];
#pragma unroll
    for (int e = 1; e < 2 * NCA; ++e) mA = fmaxf(mA, svA[e]);
#pragma unroll
    for (int e = 1; e < 2 * NCB; ++e) mB = fmaxf(mB, svB[e]);
#pragma unroll
    for (int off = 32; off; off >>= 1) {
        mA = fmaxf(mA, __shfl_xor(mA, off));
        mB = fmaxf(mB, __shfl_xor(mB, off));
    }
    float lamA = mA + 1.0f, lamB = mB + 1.0f;

    for (int it = 0; it < NUM_ITER; ++it) {
        float fA = 0.f, fpA = 0.f, fB = 0.f, fpB = 0.f;
#pragma unroll
        for (int e = 0; e < 2 * NCA; ++e) {
            const float iA = __builtin_amdgcn_rcpf(fmaxf(lamA - svA[e], EPS));
            fA += iA; fpA = fmaf(iA, iA, fpA);
        }
#pragma unroll
        for (int e = 0; e < 2 * NCB; ++e) {
            const float iB = __builtin_amdgcn_rcpf(fmaxf(lamB - svB[e], EPS));
            fB += iB; fpB = fmaf(iB, iB, fpB);
        }
#pragma unroll
        for (int off = 32; off; off >>= 1) {
            fA += __shfl_xor(fA, off); fpA += __shfl_xor(fpA, off);
            fB += __shfl_xor(fB, off); fpB += __shfl_xor(fpB, off);
        }
        lamA += (fA - 1.0f) / fpA;
        lamB += (fB - 1.0f) / fpB;
    }

    float swA = 0.f, swB = 0.f;
#pragma unroll
    for (int e = 0; e < 2 * NCA; ++e) {
        svA[e] = __builtin_amdgcn_rcpf(fmaxf(lamA - svA[e], EPS)); swA += svA[e];
    }
#pragma unroll
    for (int e = 0; e < 2 * NCB; ++e) {
        svB[e] = __builtin_amdgcn_rcpf(fmaxf(lamB - svB[e], EPS)); swB += svB[e];
    }
#pragma unroll
    for (int off = 32; off; off >>= 1) {
        swA += __shfl_xor(swA, off);
        swB += __shfl_xor(swB, off);
    }
    const float iswA = __builtin_amdgcn_rcpf(swA);
    const float iswB = __builtin_amdgcn_rcpf(swB);

#pragma unroll
    for (int t = 0; t < NCA; ++t) {
        const int c = lane * 2 + t * 128;
        if (t * 128 < limitA && c < limitA) {
            const unsigned int pk = (unsigned)f2bf_u(svA[2 * t] * iswA)
                                  | ((unsigned)f2bf_u(svA[2 * t + 1] * iswA) << 16);
            *reinterpret_cast<unsigned int*>(&SA[c]) = pk;
        }
    }
#pragma unroll
    for (int t = 0; t < NCB; ++t) {
        const int c = lane * 2 + t * 128;
        if (t * 128 < limitB && c < limitB) {
            const unsigned int pk = (unsigned)f2bf_u(svB[2 * t] * iswB)
                                  | ((unsigned)f2bf_u(svB[2 * t + 1] * iswB) << 16);
            *reinterpret_cast<unsigned int*>(&SB[c]) = pk;
        }
    }
}

// ---------------------------------------------------------------------------
// MFMA Stieltjes attention, PAIRED TILES: block = (b,h, qtA, qtB=63-qtA).
// Constant work per block (P1: 67 tasks; P2: const-length row pairs; P3:
// all 8 waves).  S holds both tiles: A cols [0, r0A+32), B at [sbBase, +r0B+32).
// ---------------------------------------------------------------------------
__global__ __launch_bounds__(512) void attn_mfma(const __hip_bfloat16* __restrict__ qkvb,
                                                 const __hip_bfloat16* __restrict__ Vt,
                                                 __hip_bfloat16* __restrict__ obf) {
    const int tid  = threadIdx.x;
    const int lane = tid & 63;
    const int wave = tid >> 6;               // 0..7
    const int pair = blockIdx.x & 31;
    const int bh = blockIdx.x >> 5;
    const int b = bh >> 4, h = bh & 15;
    const int qtA = pair, qtB = 63 - pair;
    const int r0A = qtA * 16, r0B = qtB * 16;
    const int sbBase = r0A + 32;             // 16-elem multiple -> 32B aligned

    __shared__ __align__(16) unsigned short S[16][SPAD_T];

    const size_t qbase = (size_t)(b * NSEQ) * 3072;
    const int lr  = lane & 15;
    const int lk8 = (lane >> 4) * 8;
    const int rj0 = (lane >> 4) * 4;

    // ---- Q fragments for both tiles (from global; L1/L2-hot) ----
    const __hip_bfloat16* qrowA = qkvb + qbase + (size_t)(r0A + lr) * 3072 + h * 64;
    const __hip_bfloat16* qrowB = qkvb + qbase + (size_t)(r0B + lr) * 3072 + h * 64;
    const bfrag aA0 = *reinterpret_cast<const bfrag*>(&qrowA[lk8]);
    const bfrag aA1 = *reinterpret_cast<const bfrag*>(&qrowA[32 + lk8]);
    const bfrag aB0 = *reinterpret_cast<const bfrag*>(&qrowB[lk8]);
    const bfrag aB1 = *reinterpret_cast<const bfrag*>(&qrowB[32 + lk8]);
    const __hip_bfloat16* kglob = qkvb + qbase + 1024 + h * 64;

    // ---- phase 1: QK^T for both tiles; task jt==qt+1 zeroes the overread
    //      strip [r0+16, r0+32).  67 tasks total, wave-strided. ----
    const int ntA = qtA + 2, ntB = qtB + 2;
    for (int t = wave; t < ntA + ntB; t += 8) {
        const bool isA = (t < ntA);
        const int jt  = isA ? t : (t - ntA);
        const int qtX = isA ? qtA : qtB;
        const int cb  = isA ? 0 : sbBase;
        if (jt <= qtX) {
            const int jrow = jt * 16 + lr;
            const bfrag b0 = *reinterpret_cast<const bfrag*>(&kglob[(size_t)jrow * 3072 + lk8]);
            const bfrag b1 = *reinterpret_cast<const bfrag*>(&kglob[(size_t)jrow * 3072 + 32 + lk8]);
            f32x4 c = (f32x4){0.f, 0.f, 0.f, 0.f};
            c = __builtin_amdgcn_mfma_f32_16x16x32_bf16(isA ? aA0 : aB0, b0, c, 0, 0, 0);
            c = __builtin_amdgcn_mfma_f32_16x16x32_bf16(isA ? aA1 : aB1, b1, c, 0, 0, 0);
#pragma unroll
            for (int j = 0; j < 4; ++j)
                S[rj0 + j][cb + jt * 16 + lr] = f2bf_u(c[j] * SCALE);
        } else {
#pragma unroll
            for (int j = 0; j < 4; ++j)
                S[rj0 + j][cb + jt * 16 + lr] = 0;
        }
    }
    __syncthreads();

    // ---- phase 2: paired-row Newton w/ fused write-back (2 calls/wave) ----
    {
        const int limitA = r0A + 16, limitB = r0B + 16;
        for (int p = 0; p < 2; ++p) {
            const int row = wave * 2 + p;
            const int ncolsA = r0A + row + 1, ncolsB = r0B + row + 1;
            if (qtA < 16)
                newton2_wb<1, 4>(&S[row][0], &S[row][sbBase],
                                 ncolsA, ncolsB, limitA, limitB, lane);
            else
                newton2_wb<2, 3>(&S[row][0], &S[row][sbBase],
                                 ncolsA, ncolsB, limitA, limitB, lane);
        }
    }
    __syncthreads();

    // ---- phase 3: O = P.V; waves 0-3 -> tile A, 4-7 -> tile B ----
    {
        const int tile = wave >> 2, dt = wave & 3;
        const int r0t = tile ? r0B : r0A;
        const int cb  = tile ? sbBase : 0;
        const __hip_bfloat16* vtrow = Vt + ((size_t)(bh * 64 + dt * 16 + lr)) * 1024;

        f32x4 acc0 = (f32x4){0.f, 0.f, 0.f, 0.f};
        f32x4 acc1 = (f32x4){0.f, 0.f, 0.f, 0.f};
        for (int j0 = 0; j0 <= r0t; j0 += 64) {
            {
                const bfrag pa = *reinterpret_cast<const bfrag*>(&S[lr][cb + j0 + lk8]);
                const bfrag pb = *reinterpret_cast<const bfrag*>(&vtrow[j0 + lk8]);
                acc0 = __builtin_amdgcn_mfma_f32_16x16x32_bf16(pa, pb, acc0, 0, 0, 0);
            }
            if (j0 + 32 <= r0t) {
                const bfrag pa = *reinterpret_cast<const bfrag*>(&S[lr][cb + j0 + 32 + lk8]);
                const bfrag pb = *reinterpret_cast<const bfrag*>(&vtrow[j0 + 32 + lk8]);
                acc1 = __builtin_amdgcn_mfma_f32_16x16x32_bf16(pa, pb, acc1, 0, 0, 0);
            }
        }

#pragma unroll
        for (int j = 0; j < 4; ++j) {
            const int row = rj0 + j;
            obf[(size_t)(b * NSEQ + r0t + row) * 1024 + h * 64 + dt * 16 + lr] =
                __float2bfloat16(acc0[j] + acc1[j]);
        }
    }
}

extern "C" void kernel_launch(void* const* d_in, const int* in_sizes, int n_in,
                              void* d_out, int out_size, void* d_ws, size_t ws_size,
                              hipStream_t stream) {
    const float* x    = (const float*)d_in[0];   // [B,N,D]
    const float* Wqkv = (const float*)d_in[1];   // [3D, D]
    const float* Wo   = (const float*)d_in[2];   // [D, D]
    float* out = (float*)d_out;                  // [B,N,D] fp32

    const int M = BATCH * NSEQ;                  // 2048
    char* ws = (char*)d_ws;
    __hip_bfloat16* xbf  = (__hip_bfloat16*)ws; ws += (size_t)M * DMODEL * 2;
    __hip_bfloat16* wqbf = (__hip_bfloat16*)ws; ws += (size_t)3 * DMODEL * DMODEL * 2;
    __hip_bfloat16* wobf = (__hip_bfloat16*)ws; ws += (size_t)DMODEL * DMODEL * 2;
    __hip_bfloat16* qkvb = (__hip_bfloat16*)ws; ws += (size_t)M * 3 * DMODEL * 2;
    __hip_bfloat16* Vt   = (__hip_bfloat16*)ws; ws += (size_t)BATCH * HNUM * DH * NSEQ * 2;
    __hip_bfloat16* obf  = (__hip_bfloat16*)ws; ws += (size_t)M * DMODEL * 2;

    dim3 blk(256);
    cast3<<<2048, blk, 0, stream>>>(x, xbf, M * DMODEL / 4,
                                    Wqkv, wqbf, 3 * DMODEL * DMODEL / 4,
                                    Wo, wobf, DMODEL * DMODEL / 4);

    dim3 g1(3 * DMODEL / 128, M / 64);           // (24,32) = 768 blocks
    gemm_bt<true><<<g1, blk, 0, stream>>>(xbf, wqbf, qkvb, M, 3 * DMODEL, DMODEL);

    transpose_v<<<512, blk, 0, stream>>>(qkvb, Vt);

    attn_mfma<<<1024, dim3(512), 0, stream>>>(qkvb, Vt, obf);

    dim3 g2(DMODEL / 128, M / 64);               // (8,32) = 256 blocks
    gemm_bt<false><<<g2, blk, 0, stream>>>(obf, wobf, out, M, DMODEL, DMODEL);
}